// Round 5
// baseline (420.767 us; speedup 1.0000x reference)
//
#include <hip/hip_runtime.h>
#include <math.h>

// AudioPreprocessingLayer: hamming * x -> rfft(512, norm=forward).real^2
//   -> mel(20x257) -> where(==0, 2^-52) -> floor(log2)
//
// Hybrid scheme:
//   prep:   f64 twiddles (phase2), PER-LANE PACKED f32 twiddles twp[4][64]
//           (stages 0/2/4 + untangle; read from GLOBAL in phase1 -> no LDS
//           bank conflicts, R3 profile showed tw reads were the only
//           conflicted LDS access at ~124 cyc/wave), compacted filter bank
//           (support [g0,g0+ng) in 4-bin groups), meta = g0|ng<<16, count=0.
//   phase1: fp32, TWO frames per wave (float4-interleaved LDS: element e =
//           (f0.re,f0.im,f1.re,f1.im)), 4 waves/block = 8 frames/block.
//           SINGLE in-place LDS buffer per wave (Stockham stage is in-place
//           safe: every output depends on all 4 inputs, so no ds_write can
//           precede the 4 ds_reads; DS pipe is in-order per wave; buffer is
//           wave-private). 18432 B/block, launch_bounds(256,8); NO block
//           sync at all (waves fully independent; twiddles come from L1).
//           Stage 0 runs from registers; stage 6 is twiddle-free (j=0).
//           Untangle uses rex(256-k) = S_re - rex(k): one (zk,zc,wk) read
//           set yields BOTH spectrum halves, read-all-then-write.
//           Mel iterates only the compact triangular support (<=6 iters).
//           Frames with any log2(mel) within 1e-3 of an integer (or
//           mel<1e-30) are appended to a compacted worklist.
//   phase2: 4096 blocks grid-stride the worklist; each flagged frame (~4%)
//           recomputed with the R2-validated f64 pipeline (margin 1e-3 >>
//           fp32 summation-order ulps).

#define MARGIN_L2 1.0e-3f
#define IDX(e) ((e) + ((e) >> 3))   // float4 units: pad 1 per 8 elements
#define WCSTRIDE 20                 // float4 groups per mel row (>= max ng 18)

__device__ __forceinline__ float4 f4add(float4 a, float4 b) {
    return make_float4(a.x + b.x, a.y + b.y, a.z + b.z, a.w + b.w);
}
__device__ __forceinline__ float4 f4sub(float4 a, float4 b) {
    return make_float4(a.x - b.x, a.y - b.y, a.z - b.z, a.w - b.w);
}
// w=(cos,sin) meaning e^{-i*theta}; applied to both packed complex values
__device__ __forceinline__ float4 cmulc4(float2 w, float4 z) {
    return make_float4(w.x * z.x + w.y * z.y, w.x * z.y - w.y * z.x,
                       w.x * z.z + w.y * z.w, w.x * z.w - w.y * z.z);
}

// Fused radix-2^2 butterfly (validated R3 formulas), packed 2 frames.
// Twiddles are passed in (per-lane packed, loaded from global).
// In-place safe: all 4 reads are done by the caller before this writes,
// and each output depends on all 4 inputs (no write can be hoisted).
__device__ __forceinline__ void bfly4(int s, int l, float2 w1, float2 w2,
                                      float4 x1, float4 y1, float4 x2, float4 y2,
                                      float4* dst) {
    const int j = l >> s;
    const int r = l & ((1 << s) - 1);
    const float4 u1 = f4add(x1, y1);
    const float4 v1 = cmulc4(w1, f4sub(x1, y1));
    const float4 u2 = f4add(x2, y2);
    const float4 m  = cmulc4(w1, f4sub(x2, y2));
    const float4 v2 = make_float4(m.y, -m.x, m.w, -m.z);   // -i * m
    const float4 o0 = f4add(u1, u2);
    const float4 o1 = cmulc4(w2, f4sub(u1, u2));
    const float4 o2 = f4add(v1, v2);
    const float4 o3 = cmulc4(w2, f4sub(v1, v2));
    const int eb = (j << (s + 2)) + r;
    dst[IDX(eb)]            = o0;
    dst[IDX(eb + (1 << s))] = o2;
    dst[IDX(eb + (2 << s))] = o1;
    dst[IDX(eb + (3 << s))] = o3;
}

// ---------------------------------------------------------------- prep ----
__global__ void prep_full(const float* __restrict__ fb,
                          double* __restrict__ tw64,
                          float4* __restrict__ twp,   // (256,) packed per-lane
                          float4* __restrict__ wc,    // (20, WCSTRIDE) compact
                          int*    __restrict__ meta,  // (20,) g0 | ng<<16
                          unsigned* count) {
    __shared__ float2 s_tw[256];
    __shared__ int sg0[20], sng[20];
    const int t = threadIdx.x;  // 256
    double s, c;
    sincospi((double)t * (1.0 / 256.0), &s, &c);
    tw64[t]       = c;
    tw64[256 + t] = s;
    s_tw[t] = make_float2((float)c, (float)s);

    if (t < 20) {   // nonzero-support scan for mel row t
        int lo = 257, hi = 0;
        for (int k = 0; k < 257; k++) {
            if (fb[t * 257 + k] > 0.0f) {
                if (k < lo) lo = k;
                hi = k + 1;
            }
        }
        if (hi <= lo) { lo = 0; hi = 1; }         // degenerate guard
        int g0 = lo >> 2;
        int ng = ((hi + 3) >> 2) - g0;
        if (ng > WCSTRIDE) ng = WCSTRIDE;         // never binds for this bank
        sg0[t] = g0; sng[t] = ng;
        meta[t] = g0 | (ng << 16);
    }
    __syncthreads();

    if (t < 64) {
        // stage 0: w1 = tw[2l], w2 = tw[4l]   (4*63 = 252 < 256)
        const float2 a0 = s_tw[2 * t],        b0 = s_tw[4 * t];
        twp[t]        = make_float4(a0.x, a0.y, b0.x, b0.y);
        // stage 2: j = l>>2; w1 = tw[8j], w2 = tw[16j]
        const float2 a2 = s_tw[8 * (t >> 2)], b2 = s_tw[16 * (t >> 2)];
        twp[64 + t]   = make_float4(a2.x, a2.y, b2.x, b2.y);
        // stage 4: j = l>>4; w1 = tw[32j], w2 = tw[64j]
        const float2 a4 = s_tw[32 * (t >> 4)], b4 = s_tw[64 * (t >> 4)];
        twp[128 + t]  = make_float4(a4.x, a4.y, b4.x, b4.y);
        // untangle: w0 = tw[l], w1 = tw[l+64]
        const float2 u0 = s_tw[t],            u1 = s_tw[t + 64];
        twp[192 + t]  = make_float4(u0.x, u0.y, u1.x, u1.y);
    }

    for (int i = t; i < 20 * WCSTRIDE; i += 256) {
        const int m = i / WCSTRIDE, j = i % WCSTRIDE;
        float4 v = make_float4(0.0f, 0.0f, 0.0f, 0.0f);
        if (j < sng[m]) {
            const int b = (sg0[m] + j) * 4;
            const float* row = fb + m * 257;
            v.x = (b + 0 < 257) ? row[b + 0] : 0.0f;
            v.y = (b + 1 < 257) ? row[b + 1] : 0.0f;
            v.z = (b + 2 < 257) ? row[b + 2] : 0.0f;
            v.w = (b + 3 < 257) ? row[b + 3] : 0.0f;
        }
        wc[i] = v;
    }
    if (count && t == 0) *count = 0;
}

__global__ void prep_tw64(double* __restrict__ tw64) {
    const int t = threadIdx.x;
    double s, c;
    sincospi((double)t * (1.0 / 256.0), &s, &c);
    tw64[t]       = c;
    tw64[256 + t] = s;
}

// -------------------------------------------------------------- phase 1 ----
// fp32: 2 frames per wave, 4 waves per 256-thread block (8 frames/block).
// LDS = 4*288*16 = 18432 B; 8 blocks/CU; no __syncthreads at all.
__global__ __launch_bounds__(256, 8) void phase1(
    const float* __restrict__ x,      // (frames, 512)
    const float* __restrict__ hw,     // (512,)
    const float4* __restrict__ twp,   // (256,) packed per-lane twiddles (ws)
    const float4* __restrict__ wc,    // (20, WCSTRIDE) compact filter bank
    const int*    __restrict__ meta,  // (20,) g0 | ng<<16
    float* __restrict__ out,          // (frames, 20)
    unsigned* __restrict__ count,     // worklist count
    unsigned* __restrict__ worklist)  // flagged frame ids
{
    __shared__ __align__(16) float4 buf[4][288];   // 288 = IDX(255)+2 pad

    const int t = threadIdx.x;
    const int w = t >> 6;     // wave id = frame-pair slot
    const int l = t & 63;     // lane
    const int fg0 = (blockIdx.x * 4 + w) * 2;
    const int fg1 = fg0 + 1;

    // Per-lane packed twiddles from global (L1-resident, conflict-free).
    const float4 tp0 = twp[l];
    const float4 tp2 = twp[64 + l];
    const float4 tp4 = twp[128 + l];
    const float4 tpU = twp[192 + l];

    float4* const W = &buf[w][0];

    // Load + window + stage s=0 directly from registers -> W.
    // Element e holds (f0.re, f0.im, f1.re, f1.im); x1=e[l], x2=e[l+64],
    // y1=e[l+128], y2=e[l+192] -- exactly what stage 0 consumes.
    {
        const float2* xa = (const float2*)(x + (size_t)fg0 * 512);
        const float2* xb = (const float2*)(x + (size_t)fg1 * 512);
        const float2* hp = (const float2*)hw;
        const float2 h0 = hp[l],       h1 = hp[l + 64];
        const float2 h2 = hp[l + 128], h3 = hp[l + 192];
        const float2 a0 = xa[l],       a1 = xa[l + 64];
        const float2 a2 = xa[l + 128], a3 = xa[l + 192];
        const float2 b0 = xb[l],       b1 = xb[l + 64];
        const float2 b2 = xb[l + 128], b3 = xb[l + 192];
        const float4 x1 = make_float4(a0.x * h0.x, a0.y * h0.y,
                                      b0.x * h0.x, b0.y * h0.y);
        const float4 x2 = make_float4(a1.x * h1.x, a1.y * h1.y,
                                      b1.x * h1.x, b1.y * h1.y);
        const float4 y1 = make_float4(a2.x * h2.x, a2.y * h2.y,
                                      b2.x * h2.x, b2.y * h2.y);
        const float4 y2 = make_float4(a3.x * h3.x, a3.y * h3.y,
                                      b3.x * h3.x, b3.y * h3.y);
        bfly4(0, l, make_float2(tp0.x, tp0.y), make_float2(tp0.z, tp0.w),
              x1, y1, x2, y2, W);
    }
    __builtin_amdgcn_wave_barrier();   // in-wave DS order; pin compiler

    // Stage s = 2: in place (reads complete before writes within a wave;
    // every output depends on all 4 inputs).
    {
        const float4 x1 = W[IDX(l)];
        const float4 y1 = W[IDX(l + 128)];
        const float4 x2 = W[IDX(l + 64)];
        const float4 y2 = W[IDX(l + 192)];
        bfly4(2, l, make_float2(tp2.x, tp2.y), make_float2(tp2.z, tp2.w),
              x1, y1, x2, y2, W);
        __builtin_amdgcn_wave_barrier();
    }
    // Stage s = 4.
    {
        const float4 x1 = W[IDX(l)];
        const float4 y1 = W[IDX(l + 128)];
        const float4 x2 = W[IDX(l + 64)];
        const float4 y2 = W[IDX(l + 192)];
        bfly4(4, l, make_float2(tp4.x, tp4.y), make_float2(tp4.z, tp4.w),
              x1, y1, x2, y2, W);
        __builtin_amdgcn_wave_barrier();
    }
    // Stage s = 6: j = l>>6 = 0 for every lane -> w1 = w2 = (1,0);
    // cmulc4((1,0),z) == z exactly, so skip the twiddle muls.
    {
        const float4 x1 = W[IDX(l)];
        const float4 y1 = W[IDX(l + 128)];
        const float4 x2 = W[IDX(l + 64)];
        const float4 y2 = W[IDX(l + 192)];
        const float4 u1 = f4add(x1, y1);
        const float4 v1 = f4sub(x1, y1);
        const float4 u2 = f4add(x2, y2);
        const float4 m  = f4sub(x2, y2);
        const float4 v2 = make_float4(m.y, -m.x, m.w, -m.z);   // -i * m
        W[IDX(l)]       = f4add(u1, u2);
        W[IDX(l + 64)]  = f4add(v1, v2);
        W[IDX(l + 128)] = f4sub(u1, u2);
        W[IDX(l + 192)] = f4sub(v1, v2);
    }
    __builtin_amdgcn_wave_barrier();
    // Result (natural order) in W.

    // Untangle -> Re(rfft)_k, /512, square; symmetric-pair trick:
    //   rex(k)     = E + T,  E = 0.5*(zk.re+zc.re),
    //   rex(256-k) = E - T,  T = 0.5*(wk.x*(zk.im+zc.im) - wk.y*(zk.re-zc.re))
    // Lane l handles k = l (partner 256-l, l=0 -> Nyquist 256) and
    // k = l+64 (partner 192-l); lane 0 adds the self-paired k=128.
    // pwr overlays W: ALL reads are hoisted above the writes (wave_barrier
    // pins the compiler; wave lockstep + in-order DS pipe do the rest).
    float2* const pwr2 = (float2*)W;        // 264 float2, unpadded
    {
        const float4 zk0 = W[IDX(l)];
        const float4 zc0 = W[IDX((256 - l) & 255)];
        const float4 zk1 = W[IDX(l + 64)];
        const float4 zc1 = W[IDX(192 - l)];
        const float4 zm  = W[IDX(128)];          // broadcast; lane 0 uses
        const float2 w0 = make_float2(tpU.x, tpU.y);
        const float2 w1 = make_float2(tpU.z, tpU.w);
        __builtin_amdgcn_wave_barrier();         // reads done; now write

        {
            const float SrA = zk0.x + zc0.x, SiA = zk0.y + zc0.y;
            const float DrA = zk0.x - zc0.x;
            const float SrB = zk0.z + zc0.z, SiB = zk0.w + zc0.w;
            const float DrB = zk0.z - zc0.z;
            const float EA = 0.5f * SrA, TA = 0.5f * (w0.x * SiA - w0.y * DrA);
            const float EB = 0.5f * SrB, TB = 0.5f * (w0.x * SiB - w0.y * DrB);
            const float aA = (EA + TA) * (1.0f / 512.0f);
            const float aB = (EB + TB) * (1.0f / 512.0f);
            const float bA = (EA - TA) * (1.0f / 512.0f);
            const float bB = (EB - TB) * (1.0f / 512.0f);
            pwr2[l]       = make_float2(aA * aA, aB * aB);
            pwr2[256 - l] = make_float2(bA * bA, bB * bB);  // l=0: Nyquist
        }
        {
            const float SrA = zk1.x + zc1.x, SiA = zk1.y + zc1.y;
            const float DrA = zk1.x - zc1.x;
            const float SrB = zk1.z + zc1.z, SiB = zk1.w + zc1.w;
            const float DrB = zk1.z - zc1.z;
            const float EA = 0.5f * SrA, TA = 0.5f * (w1.x * SiA - w1.y * DrA);
            const float EB = 0.5f * SrB, TB = 0.5f * (w1.x * SiB - w1.y * DrB);
            const float aA = (EA + TA) * (1.0f / 512.0f);
            const float aB = (EB + TB) * (1.0f / 512.0f);
            const float bA = (EA - TA) * (1.0f / 512.0f);
            const float bB = (EB - TB) * (1.0f / 512.0f);
            pwr2[l + 64]  = make_float2(aA * aA, aB * aB);
            pwr2[192 - l] = make_float2(bA * bA, bB * bB);
        }
        if (l == 0) {   // k = 128: wk = (0,1) -> rex = zk.re exactly
            const float vA = zm.x * (1.0f / 512.0f);
            const float vB = zm.z * (1.0f / 512.0f);
            pwr2[128] = make_float2(vA * vA, vB * vB);
        }
        if (l >= 57) pwr2[257 + (l - 57)] = make_float2(0.0f, 0.0f);
    }
    __builtin_amdgcn_wave_barrier();

    // Mel over COMPACT support: lanes l<60: mel = l%20, sub = l/20; lane
    // iterates groups j = sub, sub+3, ... < ng (max 6 iters for ng<=18).
    // Group g covers bins 4g..4g+3: q0 = pw4[2g] (bins 4g,4g+1 both frames),
    // q1 = pw4[2g+1]. Out-of-support groups contribute exact 0 (wc padded).
    float accA = 0.0f, accB = 0.0f;
    if (l < 60) {
        const int mel = l % 20;
        const int sub = l / 20;
        const int mw  = meta[mel];
        const int g0m = mw & 0xffff;
        const int ngm = mw >> 16;
        const float4* wrow = wc + mel * WCSTRIDE;
        const float4* pw4  = (const float4*)pwr2 + 2 * g0m;
        for (int j = sub; j < ngm; j += 3) {
            const float4 w4 = wrow[j];
            const float4 q0 = pw4[2 * j];
            const float4 q1 = pw4[2 * j + 1];
            accA = fmaf(w4.w, q1.z, fmaf(w4.z, q1.x,
                   fmaf(w4.y, q0.z, fmaf(w4.x, q0.x, accA))));
            accB = fmaf(w4.w, q1.w, fmaf(w4.z, q1.y,
                   fmaf(w4.y, q0.w, fmaf(w4.x, q0.y, accB))));
        }
    }
    const float pA1 = __shfl(accA, l + 20);
    const float pA2 = __shfl(accA, l + 40);
    const float pB1 = __shfl(accB, l + 20);
    const float pB2 = __shfl(accB, l + 40);

    int flagA = 0, flagB = 0;
    if (l < 20) {
        const float vA = accA + pA1 + pA2;
        float flA;
        if (vA < 1e-30f) { flA = -52.0f; flagA = 1; }
        else {
            const float l2 = log2f(vA);
            flA = floorf(l2);
            flagA = (l2 - flA < MARGIN_L2) | ((flA + 1.0f - l2) < MARGIN_L2);
        }
        out[(size_t)fg0 * 20 + l] = flA;

        const float vB = accB + pB1 + pB2;
        float flB;
        if (vB < 1e-30f) { flB = -52.0f; flagB = 1; }
        else {
            const float l2 = log2f(vB);
            flB = floorf(l2);
            flagB = (l2 - flB < MARGIN_L2) | ((flB + 1.0f - l2) < MARGIN_L2);
        }
        out[(size_t)fg1 * 20 + l] = flB;
    }
    const unsigned long long bA = __ballot(flagA);
    const unsigned long long bB = __ballot(flagB);
    if (l == 0) {
        const unsigned nf = (bA != 0ULL) + (bB != 0ULL);
        if (nf) {
            unsigned idx = atomicAdd(count, nf);
            if (bA != 0ULL) worklist[idx++] = (unsigned)fg0;
            if (bB != 0ULL) worklist[idx]   = (unsigned)fg1;
        }
    }
}

// ------------------------------------------- phase 2 (worklist repair) ----
__global__ __launch_bounds__(256) void phase2_wl(
    const float* __restrict__ x,
    const float* __restrict__ fb,
    const float* __restrict__ hw,
    const double* __restrict__ tw64,
    const unsigned* __restrict__ count,
    const unsigned* __restrict__ worklist,
    float* __restrict__ out)
{
    __shared__ double Are[256], Aim[256], Bre[256], Bim[256];
    __shared__ double ltc[256], lts[256];
    __shared__ double pwr[257];

    const int t = threadIdx.x;
    ltc[t] = tw64[t];
    lts[t] = tw64[256 + t];
    __syncthreads();

    const unsigned n = *count;
    for (unsigned i = blockIdx.x; i < n; i += gridDim.x) {
        const int f = (int)worklist[i];

        {
            const float2 xv = ((const float2*)x)[(size_t)f * 256 + t];
            const float2 hv = ((const float2*)hw)[t];
            Are[t] = (double)xv.x * (double)hv.x;
            Aim[t] = (double)xv.y * (double)hv.y;
        }
        __syncthreads();

        double* sre = Are; double* sim = Aim;
        double* dre = Bre; double* dim = Bim;
        const int p = t & 127;
        const int which = t >> 7;
#pragma unroll
        for (int s = 0; s < 8; s++) {
            const int j = p >> s;
            const double ar = sre[p],       ai = sim[p];
            const double br = sre[p + 128], bi = sim[p + 128];
            double orr, oi;
            int dpos;
            if (which) {
                const int idx = j << (s + 1);
                const double wr = ltc[idx];
                const double wi = -lts[idx];
                const double ur = ar - br, ui = ai - bi;
                orr = wr * ur - wi * ui;
                oi  = wr * ui + wi * ur;
                dpos = p + ((j + 1) << s);
            } else {
                orr = ar + br;
                oi  = ai + bi;
                dpos = p + (j << s);
            }
            dre[dpos] = orr;
            dim[dpos] = oi;
            __syncthreads();
            double* tmp;
            tmp = sre; sre = dre; dre = tmp;
            tmp = sim; sim = dim; dim = tmp;
        }

        {
            const double a = sre[t], b = sim[t];
            const int t2 = (256 - t) & 255;
            const double c = sre[t2], d = sim[t2];
            const double rex = 0.5 * (a + c)
                             + 0.5 * (ltc[t] * (b + d) - lts[t] * (a - c));
            const double v = rex * (1.0 / 512.0);
            pwr[t] = v * v;
            if (t == 0) {
                const double vn = (a - b) * (1.0 / 512.0);
                pwr[256] = vn * vn;
            }
        }
        __syncthreads();

        if (t < 160) {
            const int mel = t >> 3;
            const int sub = t & 7;
            const float* wrow = fb + mel * 257;
            double acc = 0.0;
            for (int k = sub; k < 257; k += 8)
                acc = fma((double)wrow[k], pwr[k], acc);
            acc += __shfl_down(acc, 4, 8);
            acc += __shfl_down(acc, 2, 8);
            acc += __shfl_down(acc, 1, 8);
            if (sub == 0) {
                double v = acc;
                if (v == 0.0) v = 2.220446049250313e-16;
                out[(size_t)f * 20 + mel] = (float)floor(log2(v));
            }
        }
        __syncthreads();
    }
}

// ------------------------------------------------- fallback: all-f64 (R2) ----
__global__ __launch_bounds__(256) void f64_all(
    const float*  __restrict__ x,
    const float*  __restrict__ fb,
    const float*  __restrict__ hw,
    const double* __restrict__ tw,
    float* __restrict__ out)
{
    __shared__ double Are[256], Aim[256], Bre[256], Bim[256];
    __shared__ double ltc[256], lts[256];
    __shared__ double pwr[257];

    const int t = threadIdx.x;
    const int f = blockIdx.x;

    ltc[t] = tw[t];
    lts[t] = tw[256 + t];
    {
        const float2 xv = ((const float2*)x)[(size_t)f * 256 + t];
        const float2 hv = ((const float2*)hw)[t];
        Are[t] = (double)xv.x * (double)hv.x;
        Aim[t] = (double)xv.y * (double)hv.y;
    }
    __syncthreads();

    double* sre = Are; double* sim = Aim;
    double* dre = Bre; double* dim = Bim;
    const int p = t & 127;
    const int which = t >> 7;
#pragma unroll
    for (int s = 0; s < 8; s++) {
        const int j = p >> s;
        const double ar = sre[p],       ai = sim[p];
        const double br = sre[p + 128], bi = sim[p + 128];
        double orr, oi;
        int dpos;
        if (which) {
            const int idx = j << (s + 1);
            const double wr = ltc[idx];
            const double wi = -lts[idx];
            const double ur = ar - br, ui = ai - bi;
            orr = wr * ur - wi * ui;
            oi  = wr * ui + wi * ur;
            dpos = p + ((j + 1) << s);
        } else {
            orr = ar + br;
            oi  = ai + bi;
            dpos = p + (j << s);
        }
        dre[dpos] = orr;
        dim[dpos] = oi;
        __syncthreads();
        double* tmp;
        tmp = sre; sre = dre; dre = tmp;
        tmp = sim; sim = dim; dim = tmp;
    }

    {
        const double a = sre[t], b = sim[t];
        const int t2 = (256 - t) & 255;
        const double c = sre[t2], d = sim[t2];
        const double rex = 0.5 * (a + c)
                         + 0.5 * (ltc[t] * (b + d) - lts[t] * (a - c));
        const double v = rex * (1.0 / 512.0);
        pwr[t] = v * v;
        if (t == 0) {
            const double vn = (a - b) * (1.0 / 512.0);
            pwr[256] = vn * vn;
        }
    }
    __syncthreads();

    if (t < 160) {
        const int mel = t >> 3;
        const int sub = t & 7;
        const float* wrow = fb + mel * 257;
        double acc = 0.0;
        for (int k = sub; k < 257; k += 8)
            acc = fma((double)wrow[k], pwr[k], acc);
        acc += __shfl_down(acc, 4, 8);
        acc += __shfl_down(acc, 2, 8);
        acc += __shfl_down(acc, 1, 8);
        if (sub == 0) {
            double v = acc;
            if (v == 0.0) v = 2.220446049250313e-16;
            out[(size_t)f * 20 + mel] = (float)floor(log2(v));
        }
    }
}

// ---------------------------------------------------------------- launch ----
extern "C" void kernel_launch(void* const* d_in, const int* in_sizes, int n_in,
                              void* d_out, int out_size, void* d_ws, size_t ws_size,
                              hipStream_t stream) {
    const float* x  = (const float*)d_in[0];   // (4096, 32, 512) f32
    const float* fb = (const float*)d_in[1];   // (20, 257) f32
    const float* hw = (const float*)d_in[2];   // (512,) f32
    float* out = (float*)d_out;

    const int frames = in_sizes[0] / 512;      // 131072

    char* ws = (char*)d_ws;
    double* tw64 = (double*)ws;                          // 4096 B
    float4* twp  = (float4*)(ws + 4096);                 // 256*16 = 4096 B
    float4* wc   = (float4*)(ws + 8192);                 // 20*20*16 = 6400 B
    int*    meta = (int*)(ws + 14592);                   // 80 B

    const size_t T1 = 32832 + 4 * (size_t)frames;        // count + worklist

    if (ws_size >= T1 && (frames % 8) == 0) {
        unsigned* count    = (unsigned*)(ws + 32768);
        unsigned* worklist = (unsigned*)(ws + 32832);
        prep_full<<<1, 256, 0, stream>>>(fb, tw64, twp, wc, meta, count);
        phase1<<<frames / 8, 256, 0, stream>>>(x, hw, twp, wc, meta, out,
                                               count, worklist);
        phase2_wl<<<4096, 256, 0, stream>>>(x, fb, hw, tw64, count, worklist, out);
    } else {
        prep_tw64<<<1, 256, 0, stream>>>(tw64);
        f64_all<<<frames, 256, 0, stream>>>(x, fb, hw, tw64, out);
    }
}

// Round 6
// 415.911 us; speedup vs baseline: 1.0117x; 1.0117x over previous
//
#include <hip/hip_runtime.h>
#include <math.h>

// AudioPreprocessingLayer: hamming * x -> rfft(512, norm=forward).real^2
//   -> mel(20x257) -> where(==0, 2^-52) -> floor(log2)
//
// Hybrid scheme:
//   prep:   f64 twiddles (phase2), per-lane packed f32 twiddles twp[4][64],
//           compacted filter bank (support [g0,g0+ng) in 4-bin groups),
//           meta = g0|ng<<16, worklist count=0.
//   phase1: fp32, FOUR frames per wave as TWO independent chains (A,B), each
//           chain = 2 frames packed in float4 LDS elements (f0.re,f0.im,
//           f1.re,f1.im). R5 evidence: time tracks DS-instr count with all
//           pipes <50% busy at max occupancy -> intra-wave latency bubbles.
//           Two chains interleaved at source level fill each other's
//           ds_read/global-load latency (ILP=2), trading occupancy (16
//           waves/CU, LDS 36864 B/block, 4 blocks/CU) for ILP.
//           Per chain: SINGLE in-place LDS buffer (Stockham stage is
//           in-place safe: all 4 reads precede writes in program order per
//           buffer; DS pipe is in-order per wave; buffers wave-private).
//           Stage 0 from registers; stage 6 twiddle-free (j=0); untangle
//           yields both spectrum halves from one read set; mel iterates
//           only the compact triangular support (<=6 iters, 12 b128/chain).
//           Frames with any log2(mel) within 1e-3 of an integer (or
//           mel<1e-30) are appended to a compacted worklist.
//   phase2: 4096 blocks grid-stride the worklist; each flagged frame (~4%)
//           recomputed with the R2-validated f64 pipeline (margin 1e-3 >>
//           fp32 summation-order ulps).

#define MARGIN_L2 1.0e-3f
#define IDX(e) ((e) + ((e) >> 3))   // float4 units: pad 1 per 8 elements
#define WCSTRIDE 20                 // float4 groups per mel row (>= max ng 18)

__device__ __forceinline__ float4 f4add(float4 a, float4 b) {
    return make_float4(a.x + b.x, a.y + b.y, a.z + b.z, a.w + b.w);
}
__device__ __forceinline__ float4 f4sub(float4 a, float4 b) {
    return make_float4(a.x - b.x, a.y - b.y, a.z - b.z, a.w - b.w);
}
// w=(cos,sin) meaning e^{-i*theta}; applied to both packed complex values
__device__ __forceinline__ float4 cmulc4(float2 w, float4 z) {
    return make_float4(w.x * z.x + w.y * z.y, w.x * z.y - w.y * z.x,
                       w.x * z.z + w.y * z.w, w.x * z.w - w.y * z.z);
}

// Fused radix-2^2 butterfly (validated R3 formulas), packed 2 frames.
// In-place safe: all 4 reads are done by the caller before this writes,
// and each output depends on all 4 inputs (no write can be hoisted).
__device__ __forceinline__ void bfly4(int s, int l, float2 w1, float2 w2,
                                      float4 x1, float4 y1, float4 x2, float4 y2,
                                      float4* dst) {
    const int j = l >> s;
    const int r = l & ((1 << s) - 1);
    const float4 u1 = f4add(x1, y1);
    const float4 v1 = cmulc4(w1, f4sub(x1, y1));
    const float4 u2 = f4add(x2, y2);
    const float4 m  = cmulc4(w1, f4sub(x2, y2));
    const float4 v2 = make_float4(m.y, -m.x, m.w, -m.z);   // -i * m
    const float4 o0 = f4add(u1, u2);
    const float4 o1 = cmulc4(w2, f4sub(u1, u2));
    const float4 o2 = f4add(v1, v2);
    const float4 o3 = cmulc4(w2, f4sub(v1, v2));
    const int eb = (j << (s + 2)) + r;
    dst[IDX(eb)]            = o0;
    dst[IDX(eb + (1 << s))] = o2;
    dst[IDX(eb + (2 << s))] = o1;
    dst[IDX(eb + (3 << s))] = o3;
}

// Load + window + stage 0 from registers for one chain (2 frames).
__device__ __forceinline__ void load_stage0(
    const float* __restrict__ x, int f0, int f1, int l,
    float2 h0, float2 h1, float2 h2, float2 h3,
    float2 w1, float2 w2, float4* W)
{
    const float2* xa = (const float2*)(x + (size_t)f0 * 512);
    const float2* xb = (const float2*)(x + (size_t)f1 * 512);
    const float2 a0 = xa[l],       a1 = xa[l + 64];
    const float2 a2 = xa[l + 128], a3 = xa[l + 192];
    const float2 b0 = xb[l],       b1 = xb[l + 64];
    const float2 b2 = xb[l + 128], b3 = xb[l + 192];
    const float4 x1 = make_float4(a0.x * h0.x, a0.y * h0.y,
                                  b0.x * h0.x, b0.y * h0.y);
    const float4 x2 = make_float4(a1.x * h1.x, a1.y * h1.y,
                                  b1.x * h1.x, b1.y * h1.y);
    const float4 y1 = make_float4(a2.x * h2.x, a2.y * h2.y,
                                  b2.x * h2.x, b2.y * h2.y);
    const float4 y2 = make_float4(a3.x * h3.x, a3.y * h3.y,
                                  b3.x * h3.x, b3.y * h3.y);
    bfly4(0, l, w1, w2, x1, y1, x2, y2, W);
}

// ---------------------------------------------------------------- prep ----
__global__ void prep_full(const float* __restrict__ fb,
                          double* __restrict__ tw64,
                          float4* __restrict__ twp,   // (256,) packed per-lane
                          float4* __restrict__ wc,    // (20, WCSTRIDE) compact
                          int*    __restrict__ meta,  // (20,) g0 | ng<<16
                          unsigned* count) {
    __shared__ float2 s_tw[256];
    __shared__ int sg0[20], sng[20];
    const int t = threadIdx.x;  // 256
    double s, c;
    sincospi((double)t * (1.0 / 256.0), &s, &c);
    tw64[t]       = c;
    tw64[256 + t] = s;
    s_tw[t] = make_float2((float)c, (float)s);

    if (t < 20) {   // nonzero-support scan for mel row t
        int lo = 257, hi = 0;
        for (int k = 0; k < 257; k++) {
            if (fb[t * 257 + k] > 0.0f) {
                if (k < lo) lo = k;
                hi = k + 1;
            }
        }
        if (hi <= lo) { lo = 0; hi = 1; }         // degenerate guard
        int g0 = lo >> 2;
        int ng = ((hi + 3) >> 2) - g0;
        if (ng > WCSTRIDE) ng = WCSTRIDE;         // never binds for this bank
        sg0[t] = g0; sng[t] = ng;
        meta[t] = g0 | (ng << 16);
    }
    __syncthreads();

    if (t < 64) {
        // stage 0: w1 = tw[2l], w2 = tw[4l]   (4*63 = 252 < 256)
        const float2 a0 = s_tw[2 * t],        b0 = s_tw[4 * t];
        twp[t]        = make_float4(a0.x, a0.y, b0.x, b0.y);
        // stage 2: j = l>>2; w1 = tw[8j], w2 = tw[16j]
        const float2 a2 = s_tw[8 * (t >> 2)], b2 = s_tw[16 * (t >> 2)];
        twp[64 + t]   = make_float4(a2.x, a2.y, b2.x, b2.y);
        // stage 4: j = l>>4; w1 = tw[32j], w2 = tw[64j]
        const float2 a4 = s_tw[32 * (t >> 4)], b4 = s_tw[64 * (t >> 4)];
        twp[128 + t]  = make_float4(a4.x, a4.y, b4.x, b4.y);
        // untangle: w0 = tw[l], w1 = tw[l+64]
        const float2 u0 = s_tw[t],            u1 = s_tw[t + 64];
        twp[192 + t]  = make_float4(u0.x, u0.y, u1.x, u1.y);
    }

    for (int i = t; i < 20 * WCSTRIDE; i += 256) {
        const int m = i / WCSTRIDE, j = i % WCSTRIDE;
        float4 v = make_float4(0.0f, 0.0f, 0.0f, 0.0f);
        if (j < sng[m]) {
            const int b = (sg0[m] + j) * 4;
            const float* row = fb + m * 257;
            v.x = (b + 0 < 257) ? row[b + 0] : 0.0f;
            v.y = (b + 1 < 257) ? row[b + 1] : 0.0f;
            v.z = (b + 2 < 257) ? row[b + 2] : 0.0f;
            v.w = (b + 3 < 257) ? row[b + 3] : 0.0f;
        }
        wc[i] = v;
    }
    if (count && t == 0) *count = 0;
}

__global__ void prep_tw64(double* __restrict__ tw64) {
    const int t = threadIdx.x;
    double s, c;
    sincospi((double)t * (1.0 / 256.0), &s, &c);
    tw64[t]       = c;
    tw64[256 + t] = s;
}

// -------------------------------------------------------------- phase 1 ----
// fp32: 4 frames per wave (2 chains x 2 packed), 4 waves per 256-thread
// block (16 frames/block). LDS = 8*288*16 = 36864 B -> 4 blocks/CU.
__global__ __launch_bounds__(256, 4) void phase1(
    const float* __restrict__ x,      // (frames, 512)
    const float* __restrict__ hw,     // (512,)
    const float4* __restrict__ twp,   // (256,) packed per-lane twiddles (ws)
    const float4* __restrict__ wc,    // (20, WCSTRIDE) compact filter bank
    const int*    __restrict__ meta,  // (20,) g0 | ng<<16
    float* __restrict__ out,          // (frames, 20)
    unsigned* __restrict__ count,     // worklist count
    unsigned* __restrict__ worklist)  // flagged frame ids
{
    __shared__ __align__(16) float4 buf[8][288];   // 288 = IDX(255)+2 pad

    const int t = threadIdx.x;
    const int w = t >> 6;     // wave id
    const int l = t & 63;     // lane
    const int base = (blockIdx.x * 4 + w) * 4;
    const int fg0 = base, fg1 = base + 1, fg2 = base + 2, fg3 = base + 3;

    // Per-lane packed twiddles from global (L1-resident, conflict-free).
    const float4 tp0 = twp[l];
    const float4 tp2 = twp[64 + l];
    const float4 tp4 = twp[128 + l];
    const float4 tpU = twp[192 + l];
    const float2 w0s = make_float2(tp0.x, tp0.y), w0d = make_float2(tp0.z, tp0.w);
    const float2 w2s = make_float2(tp2.x, tp2.y), w2d = make_float2(tp2.z, tp2.w);
    const float2 w4s = make_float2(tp4.x, tp4.y), w4d = make_float2(tp4.z, tp4.w);

    float4* const WA = &buf[2 * w][0];
    float4* const WB = &buf[2 * w + 1][0];

    // Hamming window (shared by both chains).
    const float2* hp = (const float2*)hw;
    const float2 h0 = hp[l],       h1 = hp[l + 64];
    const float2 h2 = hp[l + 128], h3 = hp[l + 192];

    // Load + window + stage 0, both chains (independent DS/global streams).
    load_stage0(x, fg0, fg1, l, h0, h1, h2, h3, w0s, w0d, WA);
    load_stage0(x, fg2, fg3, l, h0, h1, h2, h3, w0s, w0d, WB);
    __builtin_amdgcn_wave_barrier();   // in-wave DS order; pin compiler

    // Stage s = 2: both chains, reads first (in-place safe per buffer).
    {
        const float4 ax1 = WA[IDX(l)],      ay1 = WA[IDX(l + 128)];
        const float4 ax2 = WA[IDX(l + 64)], ay2 = WA[IDX(l + 192)];
        const float4 bx1 = WB[IDX(l)],      by1 = WB[IDX(l + 128)];
        const float4 bx2 = WB[IDX(l + 64)], by2 = WB[IDX(l + 192)];
        bfly4(2, l, w2s, w2d, ax1, ay1, ax2, ay2, WA);
        bfly4(2, l, w2s, w2d, bx1, by1, bx2, by2, WB);
        __builtin_amdgcn_wave_barrier();
    }
    // Stage s = 4.
    {
        const float4 ax1 = WA[IDX(l)],      ay1 = WA[IDX(l + 128)];
        const float4 ax2 = WA[IDX(l + 64)], ay2 = WA[IDX(l + 192)];
        const float4 bx1 = WB[IDX(l)],      by1 = WB[IDX(l + 128)];
        const float4 bx2 = WB[IDX(l + 64)], by2 = WB[IDX(l + 192)];
        bfly4(4, l, w4s, w4d, ax1, ay1, ax2, ay2, WA);
        bfly4(4, l, w4s, w4d, bx1, by1, bx2, by2, WB);
        __builtin_amdgcn_wave_barrier();
    }
    // Stage s = 6: j = 0 for every lane -> twiddles are (1,0): skip muls.
    {
        const float4 ax1 = WA[IDX(l)],      ay1 = WA[IDX(l + 128)];
        const float4 ax2 = WA[IDX(l + 64)], ay2 = WA[IDX(l + 192)];
        const float4 bx1 = WB[IDX(l)],      by1 = WB[IDX(l + 128)];
        const float4 bx2 = WB[IDX(l + 64)], by2 = WB[IDX(l + 192)];
        {
            const float4 u1 = f4add(ax1, ay1);
            const float4 v1 = f4sub(ax1, ay1);
            const float4 u2 = f4add(ax2, ay2);
            const float4 m  = f4sub(ax2, ay2);
            const float4 v2 = make_float4(m.y, -m.x, m.w, -m.z);   // -i*m
            WA[IDX(l)]       = f4add(u1, u2);
            WA[IDX(l + 64)]  = f4add(v1, v2);
            WA[IDX(l + 128)] = f4sub(u1, u2);
            WA[IDX(l + 192)] = f4sub(v1, v2);
        }
        {
            const float4 u1 = f4add(bx1, by1);
            const float4 v1 = f4sub(bx1, by1);
            const float4 u2 = f4add(bx2, by2);
            const float4 m  = f4sub(bx2, by2);
            const float4 v2 = make_float4(m.y, -m.x, m.w, -m.z);
            WB[IDX(l)]       = f4add(u1, u2);
            WB[IDX(l + 64)]  = f4add(v1, v2);
            WB[IDX(l + 128)] = f4sub(u1, u2);
            WB[IDX(l + 192)] = f4sub(v1, v2);
        }
    }
    __builtin_amdgcn_wave_barrier();
    // Result (natural order) in WA/WB.

    // Untangle -> Re(rfft)_k, /512, square; symmetric-pair trick:
    //   rex(k)     = E + T,  E = 0.5*(zk.re+zc.re),
    //   rex(256-k) = E - T,  T = 0.5*(wk.x*(zk.im+zc.im) - wk.y*(zk.re-zc.re))
    // Lane l handles k = l (partner 256-l, l=0 -> Nyquist 256) and
    // k = l+64 (partner 192-l); lane 0 adds the self-paired k=128.
    // pwr overlays W: ALL reads hoisted above writes (wave_barrier pins).
    float2* const pwrA = (float2*)WA;       // 264 float2, unpadded
    float2* const pwrB = (float2*)WB;
    {
        const float4 zk0A = WA[IDX(l)];
        const float4 zc0A = WA[IDX((256 - l) & 255)];
        const float4 zk1A = WA[IDX(l + 64)];
        const float4 zc1A = WA[IDX(192 - l)];
        const float4 zmA  = WA[IDX(128)];
        const float4 zk0B = WB[IDX(l)];
        const float4 zc0B = WB[IDX((256 - l) & 255)];
        const float4 zk1B = WB[IDX(l + 64)];
        const float4 zc1B = WB[IDX(192 - l)];
        const float4 zmB  = WB[IDX(128)];
        const float2 u0 = make_float2(tpU.x, tpU.y);
        const float2 u1 = make_float2(tpU.z, tpU.w);
        __builtin_amdgcn_wave_barrier();         // reads done; now write

#define UNTANGLE_PAIR(zk, zc, wk, p, kk, kc)                                 \
        {                                                                    \
            const float Sr0 = zk.x + zc.x, Si0 = zk.y + zc.y;                \
            const float Dr0 = zk.x - zc.x;                                   \
            const float Sr1 = zk.z + zc.z, Si1 = zk.w + zc.w;                \
            const float Dr1 = zk.z - zc.z;                                   \
            const float E0 = 0.5f * Sr0;                                     \
            const float T0 = 0.5f * (wk.x * Si0 - wk.y * Dr0);               \
            const float E1 = 0.5f * Sr1;                                     \
            const float T1 = 0.5f * (wk.x * Si1 - wk.y * Dr1);               \
            const float a0 = (E0 + T0) * (1.0f / 512.0f);                    \
            const float a1 = (E1 + T1) * (1.0f / 512.0f);                    \
            const float b0 = (E0 - T0) * (1.0f / 512.0f);                    \
            const float b1 = (E1 - T1) * (1.0f / 512.0f);                    \
            p[kk] = make_float2(a0 * a0, a1 * a1);                           \
            p[kc] = make_float2(b0 * b0, b1 * b1);                           \
        }
        UNTANGLE_PAIR(zk0A, zc0A, u0, pwrA, l, 256 - l)        // l=0: Nyquist
        UNTANGLE_PAIR(zk1A, zc1A, u1, pwrA, l + 64, 192 - l)
        UNTANGLE_PAIR(zk0B, zc0B, u0, pwrB, l, 256 - l)
        UNTANGLE_PAIR(zk1B, zc1B, u1, pwrB, l + 64, 192 - l)
#undef UNTANGLE_PAIR
        if (l == 0) {   // k = 128: wk = (0,1) -> rex = zk.re exactly
            const float vA0 = zmA.x * (1.0f / 512.0f);
            const float vA1 = zmA.z * (1.0f / 512.0f);
            pwrA[128] = make_float2(vA0 * vA0, vA1 * vA1);
            const float vB0 = zmB.x * (1.0f / 512.0f);
            const float vB1 = zmB.z * (1.0f / 512.0f);
            pwrB[128] = make_float2(vB0 * vB0, vB1 * vB1);
        }
        if (l >= 57) {
            pwrA[257 + (l - 57)] = make_float2(0.0f, 0.0f);
            pwrB[257 + (l - 57)] = make_float2(0.0f, 0.0f);
        }
    }
    __builtin_amdgcn_wave_barrier();

    // Mel over COMPACT support: lanes l<60: mel = l%20, sub = l/20; lane
    // iterates groups j = sub, sub+3, ... < ng (max 6 iters for ng<=18).
    // Both chains in one loop: 4 b128 reads + 8 FMA-quads per iteration.
    float aA = 0.0f, aB = 0.0f, aC = 0.0f, aD = 0.0f;
    if (l < 60) {
        const int mel = l % 20;
        const int sub = l / 20;
        const int mw  = meta[mel];
        const int g0m = mw & 0xffff;
        const int ngm = mw >> 16;
        const float4* wrow = wc + mel * WCSTRIDE;
        const float4* pwA4 = (const float4*)pwrA + 2 * g0m;
        const float4* pwB4 = (const float4*)pwrB + 2 * g0m;
        for (int j = sub; j < ngm; j += 3) {
            const float4 w4  = wrow[j];
            const float4 qa0 = pwA4[2 * j];
            const float4 qa1 = pwA4[2 * j + 1];
            const float4 qb0 = pwB4[2 * j];
            const float4 qb1 = pwB4[2 * j + 1];
            aA = fmaf(w4.w, qa1.z, fmaf(w4.z, qa1.x,
                 fmaf(w4.y, qa0.z, fmaf(w4.x, qa0.x, aA))));
            aB = fmaf(w4.w, qa1.w, fmaf(w4.z, qa1.y,
                 fmaf(w4.y, qa0.w, fmaf(w4.x, qa0.y, aB))));
            aC = fmaf(w4.w, qb1.z, fmaf(w4.z, qb1.x,
                 fmaf(w4.y, qb0.z, fmaf(w4.x, qb0.x, aC))));
            aD = fmaf(w4.w, qb1.w, fmaf(w4.z, qb1.y,
                 fmaf(w4.y, qb0.w, fmaf(w4.x, qb0.y, aD))));
        }
    }
    const float pA1 = __shfl(aA, l + 20), pA2 = __shfl(aA, l + 40);
    const float pB1 = __shfl(aB, l + 20), pB2 = __shfl(aB, l + 40);
    const float pC1 = __shfl(aC, l + 20), pC2 = __shfl(aC, l + 40);
    const float pD1 = __shfl(aD, l + 20), pD2 = __shfl(aD, l + 40);

    int fl0 = 0, fl1 = 0, fl2 = 0, fl3 = 0;
    if (l < 20) {
#define FINISH(acc, p1, p2, fg, flag)                                        \
        {                                                                    \
            const float v = acc + p1 + p2;                                   \
            float fl;                                                        \
            if (v < 1e-30f) { fl = -52.0f; flag = 1; }                       \
            else {                                                           \
                const float l2 = log2f(v);                                   \
                fl = floorf(l2);                                             \
                flag = (l2 - fl < MARGIN_L2) | ((fl + 1.0f - l2) < MARGIN_L2);\
            }                                                                \
            out[(size_t)fg * 20 + l] = fl;                                   \
        }
        FINISH(aA, pA1, pA2, fg0, fl0)
        FINISH(aB, pB1, pB2, fg1, fl1)
        FINISH(aC, pC1, pC2, fg2, fl2)
        FINISH(aD, pD1, pD2, fg3, fl3)
#undef FINISH
    }
    const unsigned long long b0 = __ballot(fl0);
    const unsigned long long b1 = __ballot(fl1);
    const unsigned long long b2 = __ballot(fl2);
    const unsigned long long b3 = __ballot(fl3);
    if (l == 0) {
        const unsigned nf = (b0 != 0ULL) + (b1 != 0ULL)
                          + (b2 != 0ULL) + (b3 != 0ULL);
        if (nf) {
            unsigned idx = atomicAdd(count, nf);
            if (b0 != 0ULL) worklist[idx++] = (unsigned)fg0;
            if (b1 != 0ULL) worklist[idx++] = (unsigned)fg1;
            if (b2 != 0ULL) worklist[idx++] = (unsigned)fg2;
            if (b3 != 0ULL) worklist[idx]   = (unsigned)fg3;
        }
    }
}

// ------------------------------------------- phase 2 (worklist repair) ----
__global__ __launch_bounds__(256) void phase2_wl(
    const float* __restrict__ x,
    const float* __restrict__ fb,
    const float* __restrict__ hw,
    const double* __restrict__ tw64,
    const unsigned* __restrict__ count,
    const unsigned* __restrict__ worklist,
    float* __restrict__ out)
{
    __shared__ double Are[256], Aim[256], Bre[256], Bim[256];
    __shared__ double ltc[256], lts[256];
    __shared__ double pwr[257];

    const int t = threadIdx.x;
    ltc[t] = tw64[t];
    lts[t] = tw64[256 + t];
    __syncthreads();

    const unsigned n = *count;
    for (unsigned i = blockIdx.x; i < n; i += gridDim.x) {
        const int f = (int)worklist[i];

        {
            const float2 xv = ((const float2*)x)[(size_t)f * 256 + t];
            const float2 hv = ((const float2*)hw)[t];
            Are[t] = (double)xv.x * (double)hv.x;
            Aim[t] = (double)xv.y * (double)hv.y;
        }
        __syncthreads();

        double* sre = Are; double* sim = Aim;
        double* dre = Bre; double* dim = Bim;
        const int p = t & 127;
        const int which = t >> 7;
#pragma unroll
        for (int s = 0; s < 8; s++) {
            const int j = p >> s;
            const double ar = sre[p],       ai = sim[p];
            const double br = sre[p + 128], bi = sim[p + 128];
            double orr, oi;
            int dpos;
            if (which) {
                const int idx = j << (s + 1);
                const double wr = ltc[idx];
                const double wi = -lts[idx];
                const double ur = ar - br, ui = ai - bi;
                orr = wr * ur - wi * ui;
                oi  = wr * ui + wi * ur;
                dpos = p + ((j + 1) << s);
            } else {
                orr = ar + br;
                oi  = ai + bi;
                dpos = p + (j << s);
            }
            dre[dpos] = orr;
            dim[dpos] = oi;
            __syncthreads();
            double* tmp;
            tmp = sre; sre = dre; dre = tmp;
            tmp = sim; sim = dim; dim = tmp;
        }

        {
            const double a = sre[t], b = sim[t];
            const int t2 = (256 - t) & 255;
            const double c = sre[t2], d = sim[t2];
            const double rex = 0.5 * (a + c)
                             + 0.5 * (ltc[t] * (b + d) - lts[t] * (a - c));
            const double v = rex * (1.0 / 512.0);
            pwr[t] = v * v;
            if (t == 0) {
                const double vn = (a - b) * (1.0 / 512.0);
                pwr[256] = vn * vn;
            }
        }
        __syncthreads();

        if (t < 160) {
            const int mel = t >> 3;
            const int sub = t & 7;
            const float* wrow = fb + mel * 257;
            double acc = 0.0;
            for (int k = sub; k < 257; k += 8)
                acc = fma((double)wrow[k], pwr[k], acc);
            acc += __shfl_down(acc, 4, 8);
            acc += __shfl_down(acc, 2, 8);
            acc += __shfl_down(acc, 1, 8);
            if (sub == 0) {
                double v = acc;
                if (v == 0.0) v = 2.220446049250313e-16;
                out[(size_t)f * 20 + mel] = (float)floor(log2(v));
            }
        }
        __syncthreads();
    }
}

// ------------------------------------------------- fallback: all-f64 (R2) ----
__global__ __launch_bounds__(256) void f64_all(
    const float*  __restrict__ x,
    const float*  __restrict__ fb,
    const float*  __restrict__ hw,
    const double* __restrict__ tw,
    float* __restrict__ out)
{
    __shared__ double Are[256], Aim[256], Bre[256], Bim[256];
    __shared__ double ltc[256], lts[256];
    __shared__ double pwr[257];

    const int t = threadIdx.x;
    const int f = blockIdx.x;

    ltc[t] = tw[t];
    lts[t] = tw[256 + t];
    {
        const float2 xv = ((const float2*)x)[(size_t)f * 256 + t];
        const float2 hv = ((const float2*)hw)[t];
        Are[t] = (double)xv.x * (double)hv.x;
        Aim[t] = (double)xv.y * (double)hv.y;
    }
    __syncthreads();

    double* sre = Are; double* sim = Aim;
    double* dre = Bre; double* dim = Bim;
    const int p = t & 127;
    const int which = t >> 7;
#pragma unroll
    for (int s = 0; s < 8; s++) {
        const int j = p >> s;
        const double ar = sre[p],       ai = sim[p];
        const double br = sre[p + 128], bi = sim[p + 128];
        double orr, oi;
        int dpos;
        if (which) {
            const int idx = j << (s + 1);
            const double wr = ltc[idx];
            const double wi = -lts[idx];
            const double ur = ar - br, ui = ai - bi;
            orr = wr * ur - wi * ui;
            oi  = wr * ui + wi * ur;
            dpos = p + ((j + 1) << s);
        } else {
            orr = ar + br;
            oi  = ai + bi;
            dpos = p + (j << s);
        }
        dre[dpos] = orr;
        dim[dpos] = oi;
        __syncthreads();
        double* tmp;
        tmp = sre; sre = dre; dre = tmp;
        tmp = sim; sim = dim; dim = tmp;
    }

    {
        const double a = sre[t], b = sim[t];
        const int t2 = (256 - t) & 255;
        const double c = sre[t2], d = sim[t2];
        const double rex = 0.5 * (a + c)
                         + 0.5 * (ltc[t] * (b + d) - lts[t] * (a - c));
        const double v = rex * (1.0 / 512.0);
        pwr[t] = v * v;
        if (t == 0) {
            const double vn = (a - b) * (1.0 / 512.0);
            pwr[256] = vn * vn;
        }
    }
    __syncthreads();

    if (t < 160) {
        const int mel = t >> 3;
        const int sub = t & 7;
        const float* wrow = fb + mel * 257;
        double acc = 0.0;
        for (int k = sub; k < 257; k += 8)
            acc = fma((double)wrow[k], pwr[k], acc);
        acc += __shfl_down(acc, 4, 8);
        acc += __shfl_down(acc, 2, 8);
        acc += __shfl_down(acc, 1, 8);
        if (sub == 0) {
            double v = acc;
            if (v == 0.0) v = 2.220446049250313e-16;
            out[(size_t)f * 20 + mel] = (float)floor(log2(v));
        }
    }
}

// ---------------------------------------------------------------- launch ----
extern "C" void kernel_launch(void* const* d_in, const int* in_sizes, int n_in,
                              void* d_out, int out_size, void* d_ws, size_t ws_size,
                              hipStream_t stream) {
    const float* x  = (const float*)d_in[0];   // (4096, 32, 512) f32
    const float* fb = (const float*)d_in[1];   // (20, 257) f32
    const float* hw = (const float*)d_in[2];   // (512,) f32
    float* out = (float*)d_out;

    const int frames = in_sizes[0] / 512;      // 131072

    char* ws = (char*)d_ws;
    double* tw64 = (double*)ws;                          // 4096 B
    float4* twp  = (float4*)(ws + 4096);                 // 256*16 = 4096 B
    float4* wc   = (float4*)(ws + 8192);                 // 20*20*16 = 6400 B
    int*    meta = (int*)(ws + 14592);                   // 80 B

    const size_t T1 = 32832 + 4 * (size_t)frames;        // count + worklist

    if (ws_size >= T1 && (frames % 16) == 0) {
        unsigned* count    = (unsigned*)(ws + 32768);
        unsigned* worklist = (unsigned*)(ws + 32832);
        prep_full<<<1, 256, 0, stream>>>(fb, tw64, twp, wc, meta, count);
        phase1<<<frames / 16, 256, 0, stream>>>(x, hw, twp, wc, meta, out,
                                                count, worklist);
        phase2_wl<<<4096, 256, 0, stream>>>(x, fb, hw, tw64, count, worklist, out);
    } else {
        prep_tw64<<<1, 256, 0, stream>>>(tw64);
        f64_all<<<frames, 256, 0, stream>>>(x, fb, hw, tw64, out);
    }
}

// Round 7
// 378.475 us; speedup vs baseline: 1.1117x; 1.0989x over previous
//
#include <hip/hip_runtime.h>
#include <math.h>

// AudioPreprocessingLayer: hamming * x -> rfft(512, norm=forward).real^2
//   -> mel(20x257) -> where(==0, 2^-52) -> floor(log2)
//
// Hybrid scheme:
//   prep:   f64 twiddles (f64_all fallback), per-lane packed f32 twiddles
//           twp[4][64] (phase1), per-lane packed f64 twiddles twq[4][64]
//           (phase2), compacted filter bank (support [g0,g0+ng) in 4-bin
//           groups), meta = g0|ng<<16, count=0. Support scan parallelized
//           (12 threads/mel + LDS atomics; was 20x257 serial loads).
//   phase1: fp32, FOUR frames per wave as TWO independent chains (ILP=2),
//           each chain = 2 frames packed in float4 LDS elements. Stage 0
//           from registers; stages 2/4 in-place (in-place safe: all reads
//           precede writes in wave program order; DS pipe in-order; buffers
//           wave-private); stage 6 twiddle-free; untangle emits both
//           spectrum halves per read set; mel over compact support.
//           Frames with any log2(mel) within 1e-3 of an integer (or
//           mel<1e-30) are appended to a compacted worklist.
//   phase2: WAVE-PER-FRAME f64 repair (R6 accounting: block-per-frame
//           8-stage x __syncthreads structure was ~125us, the largest
//           controllable cost). Clone of phase1's radix-2^2 structure in
//           f64 (double2 elements, same IDX padding, same formulas), zero
//           block barriers, per-lane twq twiddles, compact-support f64 mel.
//           f64 op-order change vs old phase2 is safe: 1e-15 error vs
//           boundary distances. 2048 blocks x 4 waves >= worklist (~5k).

#define MARGIN_L2 1.0e-3f
#define IDX(e) ((e) + ((e) >> 3))   // 16B units: pad 1 per 8 elements
#define WCSTRIDE 20                 // float4 groups per mel row (>= max ng 18)

__device__ __forceinline__ float4 f4add(float4 a, float4 b) {
    return make_float4(a.x + b.x, a.y + b.y, a.z + b.z, a.w + b.w);
}
__device__ __forceinline__ float4 f4sub(float4 a, float4 b) {
    return make_float4(a.x - b.x, a.y - b.y, a.z - b.z, a.w - b.w);
}
// w=(cos,sin) meaning e^{-i*theta}; applied to both packed complex values
__device__ __forceinline__ float4 cmulc4(float2 w, float4 z) {
    return make_float4(w.x * z.x + w.y * z.y, w.x * z.y - w.y * z.x,
                       w.x * z.z + w.y * z.w, w.x * z.w - w.y * z.z);
}
__device__ __forceinline__ double2 d2add(double2 a, double2 b) {
    return make_double2(a.x + b.x, a.y + b.y);
}
__device__ __forceinline__ double2 d2sub(double2 a, double2 b) {
    return make_double2(a.x - b.x, a.y - b.y);
}
__device__ __forceinline__ double2 cmulcd(double2 w, double2 z) {
    return make_double2(w.x * z.x + w.y * z.y, w.x * z.y - w.y * z.x);
}

// Fused radix-2^2 butterfly (validated R3 formulas), packed 2 frames, f32.
__device__ __forceinline__ void bfly4(int s, int l, float2 w1, float2 w2,
                                      float4 x1, float4 y1, float4 x2, float4 y2,
                                      float4* dst) {
    const int j = l >> s;
    const int r = l & ((1 << s) - 1);
    const float4 u1 = f4add(x1, y1);
    const float4 v1 = cmulc4(w1, f4sub(x1, y1));
    const float4 u2 = f4add(x2, y2);
    const float4 m  = cmulc4(w1, f4sub(x2, y2));
    const float4 v2 = make_float4(m.y, -m.x, m.w, -m.z);   // -i * m
    const float4 o0 = f4add(u1, u2);
    const float4 o1 = cmulc4(w2, f4sub(u1, u2));
    const float4 o2 = f4add(v1, v2);
    const float4 o3 = cmulc4(w2, f4sub(v1, v2));
    const int eb = (j << (s + 2)) + r;
    dst[IDX(eb)]            = o0;
    dst[IDX(eb + (1 << s))] = o2;
    dst[IDX(eb + (2 << s))] = o1;
    dst[IDX(eb + (3 << s))] = o3;
}

// Same butterfly in f64, single frame (double2 = one complex value).
__device__ __forceinline__ void bfly4d(int s, int l, double2 w1, double2 w2,
                                       double2 x1, double2 y1, double2 x2,
                                       double2 y2, double2* dst) {
    const int j = l >> s;
    const int r = l & ((1 << s) - 1);
    const double2 u1 = d2add(x1, y1);
    const double2 v1 = cmulcd(w1, d2sub(x1, y1));
    const double2 u2 = d2add(x2, y2);
    const double2 m  = cmulcd(w1, d2sub(x2, y2));
    const double2 v2 = make_double2(m.y, -m.x);   // -i * m
    const double2 o0 = d2add(u1, u2);
    const double2 o1 = cmulcd(w2, d2sub(u1, u2));
    const double2 o2 = d2add(v1, v2);
    const double2 o3 = cmulcd(w2, d2sub(v1, v2));
    const int eb = (j << (s + 2)) + r;
    dst[IDX(eb)]            = o0;
    dst[IDX(eb + (1 << s))] = o2;
    dst[IDX(eb + (2 << s))] = o1;
    dst[IDX(eb + (3 << s))] = o3;
}

// Load + window + stage 0 from registers for one f32 chain (2 frames).
__device__ __forceinline__ void load_stage0(
    const float* __restrict__ x, int f0, int f1, int l,
    float2 h0, float2 h1, float2 h2, float2 h3,
    float2 w1, float2 w2, float4* W)
{
    const float2* xa = (const float2*)(x + (size_t)f0 * 512);
    const float2* xb = (const float2*)(x + (size_t)f1 * 512);
    const float2 a0 = xa[l],       a1 = xa[l + 64];
    const float2 a2 = xa[l + 128], a3 = xa[l + 192];
    const float2 b0 = xb[l],       b1 = xb[l + 64];
    const float2 b2 = xb[l + 128], b3 = xb[l + 192];
    const float4 x1 = make_float4(a0.x * h0.x, a0.y * h0.y,
                                  b0.x * h0.x, b0.y * h0.y);
    const float4 x2 = make_float4(a1.x * h1.x, a1.y * h1.y,
                                  b1.x * h1.x, b1.y * h1.y);
    const float4 y1 = make_float4(a2.x * h2.x, a2.y * h2.y,
                                  b2.x * h2.x, b2.y * h2.y);
    const float4 y2 = make_float4(a3.x * h3.x, a3.y * h3.y,
                                  b3.x * h3.x, b3.y * h3.y);
    bfly4(0, l, w1, w2, x1, y1, x2, y2, W);
}

// ---------------------------------------------------------------- prep ----
__global__ void prep_full(const float* __restrict__ fb,
                          double* __restrict__ tw64,
                          float4* __restrict__ twp,    // (256,) f32 per-lane
                          double4* __restrict__ twq,   // (256,) f64 per-lane
                          float4* __restrict__ wc,     // (20, WCSTRIDE)
                          int*    __restrict__ meta,   // (20,) g0 | ng<<16
                          unsigned* count) {
    __shared__ float2 s_tw[256];
    __shared__ double sc[256], ss[256];
    __shared__ int slo[20], shi[20], sg0[20], sng[20];
    const int t = threadIdx.x;  // 256
    double s, c;
    sincospi((double)t * (1.0 / 256.0), &s, &c);
    tw64[t]       = c;
    tw64[256 + t] = s;
    sc[t] = c; ss[t] = s;
    s_tw[t] = make_float2((float)c, (float)s);
    if (t < 20) { slo[t] = 257; shi[t] = 0; }
    __syncthreads();

    // Parallel nonzero-support scan: 12 threads per mel row, 22 bins each.
    if (t < 240) {
        const int m = t / 12, part = t % 12;
        const int k0 = part * 22;
        int k1 = k0 + 22; if (k1 > 257) k1 = 257;
        int lo = 257, hi = 0;
        for (int k = k0; k < k1; k++)
            if (fb[m * 257 + k] > 0.0f) { if (k < lo) lo = k; hi = k + 1; }
        if (hi > lo) { atomicMin(&slo[m], lo); atomicMax(&shi[m], hi); }
    }
    __syncthreads();

    if (t < 20) {
        int lo = slo[t], hi = shi[t];
        if (hi <= lo) { lo = 0; hi = 1; }         // degenerate guard
        int g0 = lo >> 2;
        int ng = ((hi + 3) >> 2) - g0;
        if (ng > WCSTRIDE) ng = WCSTRIDE;         // never binds for this bank
        sg0[t] = g0; sng[t] = ng;
        meta[t] = g0 | (ng << 16);
    }
    if (t < 64) {
        // stage 0: w1 = tw[2l], w2 = tw[4l]   (4*63 = 252 < 256)
        const float2 a0 = s_tw[2 * t],        b0 = s_tw[4 * t];
        twp[t]        = make_float4(a0.x, a0.y, b0.x, b0.y);
        const float2 a2 = s_tw[8 * (t >> 2)], b2 = s_tw[16 * (t >> 2)];
        twp[64 + t]   = make_float4(a2.x, a2.y, b2.x, b2.y);
        const float2 a4 = s_tw[32 * (t >> 4)], b4 = s_tw[64 * (t >> 4)];
        twp[128 + t]  = make_float4(a4.x, a4.y, b4.x, b4.y);
        const float2 u0 = s_tw[t],            u1 = s_tw[t + 64];
        twp[192 + t]  = make_float4(u0.x, u0.y, u1.x, u1.y);
        // f64 versions (phase2 wave-per-frame)
        twq[t]       = make_double4(sc[2*t], ss[2*t], sc[4*t], ss[4*t]);
        twq[64 + t]  = make_double4(sc[8*(t>>2)],  ss[8*(t>>2)],
                                    sc[16*(t>>2)], ss[16*(t>>2)]);
        twq[128 + t] = make_double4(sc[32*(t>>4)], ss[32*(t>>4)],
                                    sc[64*(t>>4)], ss[64*(t>>4)]);
        twq[192 + t] = make_double4(sc[t], ss[t], sc[t+64], ss[t+64]);
    }
    __syncthreads();

    for (int i = t; i < 20 * WCSTRIDE; i += 256) {
        const int m = i / WCSTRIDE, j = i % WCSTRIDE;
        float4 v = make_float4(0.0f, 0.0f, 0.0f, 0.0f);
        if (j < sng[m]) {
            const int b = (sg0[m] + j) * 4;
            const float* row = fb + m * 257;
            v.x = (b + 0 < 257) ? row[b + 0] : 0.0f;
            v.y = (b + 1 < 257) ? row[b + 1] : 0.0f;
            v.z = (b + 2 < 257) ? row[b + 2] : 0.0f;
            v.w = (b + 3 < 257) ? row[b + 3] : 0.0f;
        }
        wc[i] = v;
    }
    if (count && t == 0) *count = 0;
}

__global__ void prep_tw64(double* __restrict__ tw64) {
    const int t = threadIdx.x;
    double s, c;
    sincospi((double)t * (1.0 / 256.0), &s, &c);
    tw64[t]       = c;
    tw64[256 + t] = s;
}

// -------------------------------------------------------------- phase 1 ----
// fp32: 4 frames per wave (2 chains x 2 packed), 4 waves per 256-thread
// block (16 frames/block). LDS = 8*288*16 = 36864 B -> 4 blocks/CU.
__global__ __launch_bounds__(256, 4) void phase1(
    const float* __restrict__ x,      // (frames, 512)
    const float* __restrict__ hw,     // (512,)
    const float4* __restrict__ twp,   // (256,) packed per-lane twiddles (ws)
    const float4* __restrict__ wc,    // (20, WCSTRIDE) compact filter bank
    const int*    __restrict__ meta,  // (20,) g0 | ng<<16
    float* __restrict__ out,          // (frames, 20)
    unsigned* __restrict__ count,     // worklist count
    unsigned* __restrict__ worklist)  // flagged frame ids
{
    __shared__ __align__(16) float4 buf[8][288];   // 288 = IDX(255)+2 pad

    const int t = threadIdx.x;
    const int w = t >> 6;     // wave id
    const int l = t & 63;     // lane
    const int base = (blockIdx.x * 4 + w) * 4;
    const int fg0 = base, fg1 = base + 1, fg2 = base + 2, fg3 = base + 3;

    const float4 tp0 = twp[l];
    const float4 tp2 = twp[64 + l];
    const float4 tp4 = twp[128 + l];
    const float4 tpU = twp[192 + l];
    const float2 w0s = make_float2(tp0.x, tp0.y), w0d = make_float2(tp0.z, tp0.w);
    const float2 w2s = make_float2(tp2.x, tp2.y), w2d = make_float2(tp2.z, tp2.w);
    const float2 w4s = make_float2(tp4.x, tp4.y), w4d = make_float2(tp4.z, tp4.w);

    float4* const WA = &buf[2 * w][0];
    float4* const WB = &buf[2 * w + 1][0];

    const float2* hp = (const float2*)hw;
    const float2 h0 = hp[l],       h1 = hp[l + 64];
    const float2 h2 = hp[l + 128], h3 = hp[l + 192];

    load_stage0(x, fg0, fg1, l, h0, h1, h2, h3, w0s, w0d, WA);
    load_stage0(x, fg2, fg3, l, h0, h1, h2, h3, w0s, w0d, WB);
    __builtin_amdgcn_wave_barrier();   // in-wave DS order; pin compiler

    {
        const float4 ax1 = WA[IDX(l)],      ay1 = WA[IDX(l + 128)];
        const float4 ax2 = WA[IDX(l + 64)], ay2 = WA[IDX(l + 192)];
        const float4 bx1 = WB[IDX(l)],      by1 = WB[IDX(l + 128)];
        const float4 bx2 = WB[IDX(l + 64)], by2 = WB[IDX(l + 192)];
        bfly4(2, l, w2s, w2d, ax1, ay1, ax2, ay2, WA);
        bfly4(2, l, w2s, w2d, bx1, by1, bx2, by2, WB);
        __builtin_amdgcn_wave_barrier();
    }
    {
        const float4 ax1 = WA[IDX(l)],      ay1 = WA[IDX(l + 128)];
        const float4 ax2 = WA[IDX(l + 64)], ay2 = WA[IDX(l + 192)];
        const float4 bx1 = WB[IDX(l)],      by1 = WB[IDX(l + 128)];
        const float4 bx2 = WB[IDX(l + 64)], by2 = WB[IDX(l + 192)];
        bfly4(4, l, w4s, w4d, ax1, ay1, ax2, ay2, WA);
        bfly4(4, l, w4s, w4d, bx1, by1, bx2, by2, WB);
        __builtin_amdgcn_wave_barrier();
    }
    // Stage s = 6: j = 0 for every lane -> twiddles are (1,0): skip muls.
    {
        const float4 ax1 = WA[IDX(l)],      ay1 = WA[IDX(l + 128)];
        const float4 ax2 = WA[IDX(l + 64)], ay2 = WA[IDX(l + 192)];
        const float4 bx1 = WB[IDX(l)],      by1 = WB[IDX(l + 128)];
        const float4 bx2 = WB[IDX(l + 64)], by2 = WB[IDX(l + 192)];
        {
            const float4 u1 = f4add(ax1, ay1);
            const float4 v1 = f4sub(ax1, ay1);
            const float4 u2 = f4add(ax2, ay2);
            const float4 m  = f4sub(ax2, ay2);
            const float4 v2 = make_float4(m.y, -m.x, m.w, -m.z);   // -i*m
            WA[IDX(l)]       = f4add(u1, u2);
            WA[IDX(l + 64)]  = f4add(v1, v2);
            WA[IDX(l + 128)] = f4sub(u1, u2);
            WA[IDX(l + 192)] = f4sub(v1, v2);
        }
        {
            const float4 u1 = f4add(bx1, by1);
            const float4 v1 = f4sub(bx1, by1);
            const float4 u2 = f4add(bx2, by2);
            const float4 m  = f4sub(bx2, by2);
            const float4 v2 = make_float4(m.y, -m.x, m.w, -m.z);
            WB[IDX(l)]       = f4add(u1, u2);
            WB[IDX(l + 64)]  = f4add(v1, v2);
            WB[IDX(l + 128)] = f4sub(u1, u2);
            WB[IDX(l + 192)] = f4sub(v1, v2);
        }
    }
    __builtin_amdgcn_wave_barrier();

    // Untangle -> Re(rfft)_k, /512, square; symmetric-pair trick.
    float2* const pwrA = (float2*)WA;       // 264 float2, unpadded
    float2* const pwrB = (float2*)WB;
    {
        const float4 zk0A = WA[IDX(l)];
        const float4 zc0A = WA[IDX((256 - l) & 255)];
        const float4 zk1A = WA[IDX(l + 64)];
        const float4 zc1A = WA[IDX(192 - l)];
        const float4 zmA  = WA[IDX(128)];
        const float4 zk0B = WB[IDX(l)];
        const float4 zc0B = WB[IDX((256 - l) & 255)];
        const float4 zk1B = WB[IDX(l + 64)];
        const float4 zc1B = WB[IDX(192 - l)];
        const float4 zmB  = WB[IDX(128)];
        const float2 u0 = make_float2(tpU.x, tpU.y);
        const float2 u1 = make_float2(tpU.z, tpU.w);
        __builtin_amdgcn_wave_barrier();         // reads done; now write

#define UNTANGLE_PAIR(zk, zc, wk, p, kk, kc)                                 \
        {                                                                    \
            const float Sr0 = zk.x + zc.x, Si0 = zk.y + zc.y;                \
            const float Dr0 = zk.x - zc.x;                                   \
            const float Sr1 = zk.z + zc.z, Si1 = zk.w + zc.w;                \
            const float Dr1 = zk.z - zc.z;                                   \
            const float E0 = 0.5f * Sr0;                                     \
            const float T0 = 0.5f * (wk.x * Si0 - wk.y * Dr0);               \
            const float E1 = 0.5f * Sr1;                                     \
            const float T1 = 0.5f * (wk.x * Si1 - wk.y * Dr1);               \
            const float a0 = (E0 + T0) * (1.0f / 512.0f);                    \
            const float a1 = (E1 + T1) * (1.0f / 512.0f);                    \
            const float b0 = (E0 - T0) * (1.0f / 512.0f);                    \
            const float b1 = (E1 - T1) * (1.0f / 512.0f);                    \
            p[kk] = make_float2(a0 * a0, a1 * a1);                           \
            p[kc] = make_float2(b0 * b0, b1 * b1);                           \
        }
        UNTANGLE_PAIR(zk0A, zc0A, u0, pwrA, l, 256 - l)        // l=0: Nyquist
        UNTANGLE_PAIR(zk1A, zc1A, u1, pwrA, l + 64, 192 - l)
        UNTANGLE_PAIR(zk0B, zc0B, u0, pwrB, l, 256 - l)
        UNTANGLE_PAIR(zk1B, zc1B, u1, pwrB, l + 64, 192 - l)
#undef UNTANGLE_PAIR
        if (l == 0) {   // k = 128: wk = (0,1) -> rex = zk.re exactly
            const float vA0 = zmA.x * (1.0f / 512.0f);
            const float vA1 = zmA.z * (1.0f / 512.0f);
            pwrA[128] = make_float2(vA0 * vA0, vA1 * vA1);
            const float vB0 = zmB.x * (1.0f / 512.0f);
            const float vB1 = zmB.z * (1.0f / 512.0f);
            pwrB[128] = make_float2(vB0 * vB0, vB1 * vB1);
        }
        if (l >= 57) {
            pwrA[257 + (l - 57)] = make_float2(0.0f, 0.0f);
            pwrB[257 + (l - 57)] = make_float2(0.0f, 0.0f);
        }
    }
    __builtin_amdgcn_wave_barrier();

    // Mel over COMPACT support, both chains.
    float aA = 0.0f, aB = 0.0f, aC = 0.0f, aD = 0.0f;
    if (l < 60) {
        const int mel = l % 20;
        const int sub = l / 20;
        const int mw  = meta[mel];
        const int g0m = mw & 0xffff;
        const int ngm = mw >> 16;
        const float4* wrow = wc + mel * WCSTRIDE;
        const float4* pwA4 = (const float4*)pwrA + 2 * g0m;
        const float4* pwB4 = (const float4*)pwrB + 2 * g0m;
        for (int j = sub; j < ngm; j += 3) {
            const float4 w4  = wrow[j];
            const float4 qa0 = pwA4[2 * j];
            const float4 qa1 = pwA4[2 * j + 1];
            const float4 qb0 = pwB4[2 * j];
            const float4 qb1 = pwB4[2 * j + 1];
            aA = fmaf(w4.w, qa1.z, fmaf(w4.z, qa1.x,
                 fmaf(w4.y, qa0.z, fmaf(w4.x, qa0.x, aA))));
            aB = fmaf(w4.w, qa1.w, fmaf(w4.z, qa1.y,
                 fmaf(w4.y, qa0.w, fmaf(w4.x, qa0.y, aB))));
            aC = fmaf(w4.w, qb1.z, fmaf(w4.z, qb1.x,
                 fmaf(w4.y, qb0.z, fmaf(w4.x, qb0.x, aC))));
            aD = fmaf(w4.w, qb1.w, fmaf(w4.z, qb1.y,
                 fmaf(w4.y, qb0.w, fmaf(w4.x, qb0.y, aD))));
        }
    }
    const float pA1 = __shfl(aA, l + 20), pA2 = __shfl(aA, l + 40);
    const float pB1 = __shfl(aB, l + 20), pB2 = __shfl(aB, l + 40);
    const float pC1 = __shfl(aC, l + 20), pC2 = __shfl(aC, l + 40);
    const float pD1 = __shfl(aD, l + 20), pD2 = __shfl(aD, l + 40);

    int fl0 = 0, fl1 = 0, fl2 = 0, fl3 = 0;
    if (l < 20) {
#define FINISH(acc, p1, p2, fg, flag)                                        \
        {                                                                    \
            const float v = acc + p1 + p2;                                   \
            float fl;                                                        \
            if (v < 1e-30f) { fl = -52.0f; flag = 1; }                       \
            else {                                                           \
                const float l2 = log2f(v);                                   \
                fl = floorf(l2);                                             \
                flag = (l2 - fl < MARGIN_L2) | ((fl + 1.0f - l2) < MARGIN_L2);\
            }                                                                \
            out[(size_t)fg * 20 + l] = fl;                                   \
        }
        FINISH(aA, pA1, pA2, fg0, fl0)
        FINISH(aB, pB1, pB2, fg1, fl1)
        FINISH(aC, pC1, pC2, fg2, fl2)
        FINISH(aD, pD1, pD2, fg3, fl3)
#undef FINISH
    }
    const unsigned long long b0 = __ballot(fl0);
    const unsigned long long b1 = __ballot(fl1);
    const unsigned long long b2 = __ballot(fl2);
    const unsigned long long b3 = __ballot(fl3);
    if (l == 0) {
        const unsigned nf = (b0 != 0ULL) + (b1 != 0ULL)
                          + (b2 != 0ULL) + (b3 != 0ULL);
        if (nf) {
            unsigned idx = atomicAdd(count, nf);
            if (b0 != 0ULL) worklist[idx++] = (unsigned)fg0;
            if (b1 != 0ULL) worklist[idx++] = (unsigned)fg1;
            if (b2 != 0ULL) worklist[idx++] = (unsigned)fg2;
            if (b3 != 0ULL) worklist[idx]   = (unsigned)fg3;
        }
    }
}

// ---------------------- phase 2 (worklist repair, wave-per-frame f64) ----
// One wave = one frame. f64 clone of phase1's radix-2^2 structure: stage 0
// from registers, stages 2/4 in-place, stage 6 twiddle-free, symmetric-pair
// untangle, compact-support f64 mel. No __syncthreads anywhere.
// LDS = 4 waves * 288 * 16 B = 18432 B.
__global__ __launch_bounds__(256, 4) void phase2_wl(
    const float* __restrict__ x,
    const float* __restrict__ hw,
    const double4* __restrict__ twq,  // (256,) per-lane f64 twiddles (ws)
    const float4* __restrict__ wc,    // (20, WCSTRIDE) compact filter bank
    const int*    __restrict__ meta,  // (20,) g0 | ng<<16
    const unsigned* __restrict__ count,
    const unsigned* __restrict__ worklist,
    float* __restrict__ out)
{
    __shared__ __align__(16) double2 dbuf[4][288];

    const int t = threadIdx.x;
    const int w = t >> 6;
    const int l = t & 63;
    double2* const W = &dbuf[w][0];
    double* const pwr = (double*)W;   // 257 (+3 pad) doubles, unpadded overlay

    const unsigned n = *count;
    const unsigned stride = gridDim.x * 4;
    for (unsigned i = blockIdx.x * 4 + (unsigned)w; i < n; i += stride) {
        const int f = (int)worklist[i];

        {   // load + window + stage 0 from registers
            const double4 tq = twq[l];
            const float2* xa = (const float2*)(x + (size_t)f * 512);
            const float2* hp = (const float2*)hw;
            const float2 a0 = xa[l],       a1 = xa[l + 64];
            const float2 a2 = xa[l + 128], a3 = xa[l + 192];
            const float2 h0 = hp[l],       h1 = hp[l + 64];
            const float2 h2 = hp[l + 128], h3 = hp[l + 192];
            const double2 x1 = make_double2((double)a0.x * (double)h0.x,
                                            (double)a0.y * (double)h0.y);
            const double2 x2 = make_double2((double)a1.x * (double)h1.x,
                                            (double)a1.y * (double)h1.y);
            const double2 y1 = make_double2((double)a2.x * (double)h2.x,
                                            (double)a2.y * (double)h2.y);
            const double2 y2 = make_double2((double)a3.x * (double)h3.x,
                                            (double)a3.y * (double)h3.y);
            bfly4d(0, l, make_double2(tq.x, tq.y), make_double2(tq.z, tq.w),
                   x1, y1, x2, y2, W);
        }
        __builtin_amdgcn_wave_barrier();
        {   // stage 2 in place
            const double4 tq = twq[64 + l];
            const double2 x1 = W[IDX(l)],      y1 = W[IDX(l + 128)];
            const double2 x2 = W[IDX(l + 64)], y2 = W[IDX(l + 192)];
            bfly4d(2, l, make_double2(tq.x, tq.y), make_double2(tq.z, tq.w),
                   x1, y1, x2, y2, W);
        }
        __builtin_amdgcn_wave_barrier();
        {   // stage 4 in place
            const double4 tq = twq[128 + l];
            const double2 x1 = W[IDX(l)],      y1 = W[IDX(l + 128)];
            const double2 x2 = W[IDX(l + 64)], y2 = W[IDX(l + 192)];
            bfly4d(4, l, make_double2(tq.x, tq.y), make_double2(tq.z, tq.w),
                   x1, y1, x2, y2, W);
        }
        __builtin_amdgcn_wave_barrier();
        {   // stage 6: twiddles are (1,0) -> skip muls
            const double2 x1 = W[IDX(l)],      y1 = W[IDX(l + 128)];
            const double2 x2 = W[IDX(l + 64)], y2 = W[IDX(l + 192)];
            const double2 u1 = d2add(x1, y1);
            const double2 v1 = d2sub(x1, y1);
            const double2 u2 = d2add(x2, y2);
            const double2 m  = d2sub(x2, y2);
            const double2 v2 = make_double2(m.y, -m.x);   // -i*m
            W[IDX(l)]       = d2add(u1, u2);
            W[IDX(l + 64)]  = d2add(v1, v2);
            W[IDX(l + 128)] = d2sub(u1, u2);
            W[IDX(l + 192)] = d2sub(v1, v2);
        }
        __builtin_amdgcn_wave_barrier();
        {   // untangle -> pwr (reads hoisted above overlay writes)
            const double4 tq = twq[192 + l];
            const double2 zk0 = W[IDX(l)];
            const double2 zc0 = W[IDX((256 - l) & 255)];
            const double2 zk1 = W[IDX(l + 64)];
            const double2 zc1 = W[IDX(192 - l)];
            const double2 zm  = W[IDX(128)];
            __builtin_amdgcn_wave_barrier();   // reads done; now write
            {
                const double Sr = zk0.x + zc0.x, Si = zk0.y + zc0.y;
                const double Dr = zk0.x - zc0.x;
                const double E = 0.5 * Sr, T = 0.5 * (tq.x * Si - tq.y * Dr);
                const double a = (E + T) * (1.0 / 512.0);
                const double b = (E - T) * (1.0 / 512.0);
                pwr[l]       = a * a;
                pwr[256 - l] = b * b;          // l=0: Nyquist
            }
            {
                const double Sr = zk1.x + zc1.x, Si = zk1.y + zc1.y;
                const double Dr = zk1.x - zc1.x;
                const double E = 0.5 * Sr, T = 0.5 * (tq.z * Si - tq.w * Dr);
                const double a = (E + T) * (1.0 / 512.0);
                const double b = (E - T) * (1.0 / 512.0);
                pwr[l + 64]  = a * a;
                pwr[192 - l] = b * b;
            }
            if (l == 0) {   // k = 128: wk = (0,1) -> rex = zk.re exactly
                const double v = zm.x * (1.0 / 512.0);
                pwr[128] = v * v;
            }
            if (l < 3) pwr[257 + l] = 0.0;     // pad for last 4-bin group
        }
        __builtin_amdgcn_wave_barrier();

        // mel over compact support, f64
        double acc = 0.0;
        if (l < 60) {
            const int mel = l % 20;
            const int sub = l / 20;
            const int mw  = meta[mel];
            const int g0m = mw & 0xffff;
            const int ngm = mw >> 16;
            const float4* wrow = wc + mel * WCSTRIDE;
            const double2* pw2 = (const double2*)pwr + 2 * g0m;
            for (int j = sub; j < ngm; j += 3) {
                const float4 w4 = wrow[j];
                const double2 q0 = pw2[2 * j];
                const double2 q1 = pw2[2 * j + 1];
                acc = fma((double)w4.x, q0.x, acc);
                acc = fma((double)w4.y, q0.y, acc);
                acc = fma((double)w4.z, q1.x, acc);
                acc = fma((double)w4.w, q1.y, acc);
            }
        }
        const double p1 = __shfl(acc, l + 20);
        const double p2 = __shfl(acc, l + 40);
        if (l < 20) {
            double v = acc + p1 + p2;
            if (v == 0.0) v = 2.220446049250313e-16;
            out[(size_t)f * 20 + l] = (float)floor(log2(v));
        }
        __builtin_amdgcn_wave_barrier();   // W reuse next iteration
    }
}

// ------------------------------------------------- fallback: all-f64 (R2) ----
__global__ __launch_bounds__(256) void f64_all(
    const float*  __restrict__ x,
    const float*  __restrict__ fb,
    const float*  __restrict__ hw,
    const double* __restrict__ tw,
    float* __restrict__ out)
{
    __shared__ double Are[256], Aim[256], Bre[256], Bim[256];
    __shared__ double ltc[256], lts[256];
    __shared__ double pwr[257];

    const int t = threadIdx.x;
    const int f = blockIdx.x;

    ltc[t] = tw[t];
    lts[t] = tw[256 + t];
    {
        const float2 xv = ((const float2*)x)[(size_t)f * 256 + t];
        const float2 hv = ((const float2*)hw)[t];
        Are[t] = (double)xv.x * (double)hv.x;
        Aim[t] = (double)xv.y * (double)hv.y;
    }
    __syncthreads();

    double* sre = Are; double* sim = Aim;
    double* dre = Bre; double* dim = Bim;
    const int p = t & 127;
    const int which = t >> 7;
#pragma unroll
    for (int s = 0; s < 8; s++) {
        const int j = p >> s;
        const double ar = sre[p],       ai = sim[p];
        const double br = sre[p + 128], bi = sim[p + 128];
        double orr, oi;
        int dpos;
        if (which) {
            const int idx = j << (s + 1);
            const double wr = ltc[idx];
            const double wi = -lts[idx];
            const double ur = ar - br, ui = ai - bi;
            orr = wr * ur - wi * ui;
            oi  = wr * ui + wi * ur;
            dpos = p + ((j + 1) << s);
        } else {
            orr = ar + br;
            oi  = ai + bi;
            dpos = p + (j << s);
        }
        dre[dpos] = orr;
        dim[dpos] = oi;
        __syncthreads();
        double* tmp;
        tmp = sre; sre = dre; dre = tmp;
        tmp = sim; sim = dim; dim = tmp;
    }

    {
        const double a = sre[t], b = sim[t];
        const int t2 = (256 - t) & 255;
        const double c = sre[t2], d = sim[t2];
        const double rex = 0.5 * (a + c)
                         + 0.5 * (ltc[t] * (b + d) - lts[t] * (a - c));
        const double v = rex * (1.0 / 512.0);
        pwr[t] = v * v;
        if (t == 0) {
            const double vn = (a - b) * (1.0 / 512.0);
            pwr[256] = vn * vn;
        }
    }
    __syncthreads();

    if (t < 160) {
        const int mel = t >> 3;
        const int sub = t & 7;
        const float* wrow = fb + mel * 257;
        double acc = 0.0;
        for (int k = sub; k < 257; k += 8)
            acc = fma((double)wrow[k], pwr[k], acc);
        acc += __shfl_down(acc, 4, 8);
        acc += __shfl_down(acc, 2, 8);
        acc += __shfl_down(acc, 1, 8);
        if (sub == 0) {
            double v = acc;
            if (v == 0.0) v = 2.220446049250313e-16;
            out[(size_t)f * 20 + mel] = (float)floor(log2(v));
        }
    }
}

// ---------------------------------------------------------------- launch ----
extern "C" void kernel_launch(void* const* d_in, const int* in_sizes, int n_in,
                              void* d_out, int out_size, void* d_ws, size_t ws_size,
                              hipStream_t stream) {
    const float* x  = (const float*)d_in[0];   // (4096, 32, 512) f32
    const float* fb = (const float*)d_in[1];   // (20, 257) f32
    const float* hw = (const float*)d_in[2];   // (512,) f32
    float* out = (float*)d_out;

    const int frames = in_sizes[0] / 512;      // 131072

    char* ws = (char*)d_ws;
    double*  tw64 = (double*)ws;                         // 4096 B
    float4*  twp  = (float4*)(ws + 4096);                // 4096 B
    float4*  wc   = (float4*)(ws + 8192);                // 6400 B
    int*     meta = (int*)(ws + 14592);                  // 80 B
    double4* twq  = (double4*)(ws + 16384);              // 8192 B

    const size_t T1 = 32832 + 4 * (size_t)frames;        // count + worklist

    if (ws_size >= T1 && (frames % 16) == 0) {
        unsigned* count    = (unsigned*)(ws + 32768);
        unsigned* worklist = (unsigned*)(ws + 32832);
        prep_full<<<1, 256, 0, stream>>>(fb, tw64, twp, twq, wc, meta, count);
        phase1<<<frames / 16, 256, 0, stream>>>(x, hw, twp, wc, meta, out,
                                                count, worklist);
        phase2_wl<<<2048, 256, 0, stream>>>(x, hw, twq, wc, meta,
                                            count, worklist, out);
    } else {
        prep_tw64<<<1, 256, 0, stream>>>(tw64);
        f64_all<<<frames, 256, 0, stream>>>(x, fb, hw, tw64, out);
    }
}

// Round 8
// 377.900 us; speedup vs baseline: 1.1134x; 1.0015x over previous
//
#include <hip/hip_runtime.h>
#include <math.h>

// AudioPreprocessingLayer: hamming * x -> rfft(512, norm=forward).real^2
//   -> mel(20x257) -> where(==0, 2^-52) -> floor(log2)
//
// Two-dispatch scheme (R8: ledger showed ~20us/dispatch overhead; phase2
// merged into phase1 as inline wave-local f64 repair):
//   prep:   per-lane packed f32 twiddles twp[4][64] (phase1 fp32 path),
//           per-lane packed f64 twiddles twq[4][64] (inline repair),
//           compacted filter bank (support [g0,g0+ng) in 4-bin groups),
//           meta = g0|ng<<16. Parallel support scan (12 threads/mel).
//   phase1: fp32, FOUR frames per wave as TWO independent chains (ILP=2),
//           each chain = 2 frames packed in float4 LDS elements. Stage 0
//           from registers; stages 2/4 in-place (in-place safe: all reads
//           precede writes in wave program order; DS pipe in-order; buffers
//           wave-private); stage 6 twiddle-free; untangle emits both
//           spectrum halves per read set; mel over compact support.
//           Frames with any log2(mel) within 1e-3 of an integer (or
//           mel<1e-30) are REPAIRED INLINE by the same wave with the
//           R7-validated wave-per-frame f64 pipeline (double2 reinterpret
//           of the wave's own float4[288] buffer -- identical 4608 B).
//           ~4% of frames -> ~15% of waves take the (wave-uniform) slow
//           path; no worklist, no atomics, no extra dispatch.

#define MARGIN_L2 1.0e-3f
#define IDX(e) ((e) + ((e) >> 3))   // 16B units: pad 1 per 8 elements
#define WCSTRIDE 20                 // float4 groups per mel row (>= max ng 18)

__device__ __forceinline__ float4 f4add(float4 a, float4 b) {
    return make_float4(a.x + b.x, a.y + b.y, a.z + b.z, a.w + b.w);
}
__device__ __forceinline__ float4 f4sub(float4 a, float4 b) {
    return make_float4(a.x - b.x, a.y - b.y, a.z - b.z, a.w - b.w);
}
// w=(cos,sin) meaning e^{-i*theta}; applied to both packed complex values
__device__ __forceinline__ float4 cmulc4(float2 w, float4 z) {
    return make_float4(w.x * z.x + w.y * z.y, w.x * z.y - w.y * z.x,
                       w.x * z.z + w.y * z.w, w.x * z.w - w.y * z.z);
}
__device__ __forceinline__ double2 d2add(double2 a, double2 b) {
    return make_double2(a.x + b.x, a.y + b.y);
}
__device__ __forceinline__ double2 d2sub(double2 a, double2 b) {
    return make_double2(a.x - b.x, a.y - b.y);
}
__device__ __forceinline__ double2 cmulcd(double2 w, double2 z) {
    return make_double2(w.x * z.x + w.y * z.y, w.x * z.y - w.y * z.x);
}

// Fused radix-2^2 butterfly (validated R3 formulas), packed 2 frames, f32.
__device__ __forceinline__ void bfly4(int s, int l, float2 w1, float2 w2,
                                      float4 x1, float4 y1, float4 x2, float4 y2,
                                      float4* dst) {
    const int j = l >> s;
    const int r = l & ((1 << s) - 1);
    const float4 u1 = f4add(x1, y1);
    const float4 v1 = cmulc4(w1, f4sub(x1, y1));
    const float4 u2 = f4add(x2, y2);
    const float4 m  = cmulc4(w1, f4sub(x2, y2));
    const float4 v2 = make_float4(m.y, -m.x, m.w, -m.z);   // -i * m
    const float4 o0 = f4add(u1, u2);
    const float4 o1 = cmulc4(w2, f4sub(u1, u2));
    const float4 o2 = f4add(v1, v2);
    const float4 o3 = cmulc4(w2, f4sub(v1, v2));
    const int eb = (j << (s + 2)) + r;
    dst[IDX(eb)]            = o0;
    dst[IDX(eb + (1 << s))] = o2;
    dst[IDX(eb + (2 << s))] = o1;
    dst[IDX(eb + (3 << s))] = o3;
}

// Same butterfly in f64, single frame (double2 = one complex value).
__device__ __forceinline__ void bfly4d(int s, int l, double2 w1, double2 w2,
                                       double2 x1, double2 y1, double2 x2,
                                       double2 y2, double2* dst) {
    const int j = l >> s;
    const int r = l & ((1 << s) - 1);
    const double2 u1 = d2add(x1, y1);
    const double2 v1 = cmulcd(w1, d2sub(x1, y1));
    const double2 u2 = d2add(x2, y2);
    const double2 m  = cmulcd(w1, d2sub(x2, y2));
    const double2 v2 = make_double2(m.y, -m.x);   // -i * m
    const double2 o0 = d2add(u1, u2);
    const double2 o1 = cmulcd(w2, d2sub(u1, u2));
    const double2 o2 = d2add(v1, v2);
    const double2 o3 = cmulcd(w2, d2sub(v1, v2));
    const int eb = (j << (s + 2)) + r;
    dst[IDX(eb)]            = o0;
    dst[IDX(eb + (1 << s))] = o2;
    dst[IDX(eb + (2 << s))] = o1;
    dst[IDX(eb + (3 << s))] = o3;
}

// Load + window + stage 0 from registers for one f32 chain (2 frames).
__device__ __forceinline__ void load_stage0(
    const float* __restrict__ x, int f0, int f1, int l,
    float2 h0, float2 h1, float2 h2, float2 h3,
    float2 w1, float2 w2, float4* W)
{
    const float2* xa = (const float2*)(x + (size_t)f0 * 512);
    const float2* xb = (const float2*)(x + (size_t)f1 * 512);
    const float2 a0 = xa[l],       a1 = xa[l + 64];
    const float2 a2 = xa[l + 128], a3 = xa[l + 192];
    const float2 b0 = xb[l],       b1 = xb[l + 64];
    const float2 b2 = xb[l + 128], b3 = xb[l + 192];
    const float4 x1 = make_float4(a0.x * h0.x, a0.y * h0.y,
                                  b0.x * h0.x, b0.y * h0.y);
    const float4 x2 = make_float4(a1.x * h1.x, a1.y * h1.y,
                                  b1.x * h1.x, b1.y * h1.y);
    const float4 y1 = make_float4(a2.x * h2.x, a2.y * h2.y,
                                  b2.x * h2.x, b2.y * h2.y);
    const float4 y2 = make_float4(a3.x * h3.x, a3.y * h3.y,
                                  b3.x * h3.x, b3.y * h3.y);
    bfly4(0, l, w1, w2, x1, y1, x2, y2, W);
}

// Wave-local f64 repair of one frame (R7-validated wave-per-frame pipeline).
// W is the wave's own LDS buffer reinterpreted as double2[288] (4608 B,
// identical to float4[288]). noinline keeps the hot path's registers lean.
__device__ __attribute__((noinline)) void repair_f64(
    const float* __restrict__ x, const float* __restrict__ hw,
    const double4* __restrict__ twq, const float4* __restrict__ wc,
    const int* __restrict__ meta, float* __restrict__ out,
    int f, int l, double2* W)
{
    double* const pwr = (double*)W;   // 260 doubles overlay (unpadded)

    {   // load + window + stage 0 from registers
        const double4 tq = twq[l];
        const float2* xa = (const float2*)(x + (size_t)f * 512);
        const float2* hp = (const float2*)hw;
        const float2 a0 = xa[l],       a1 = xa[l + 64];
        const float2 a2 = xa[l + 128], a3 = xa[l + 192];
        const float2 h0 = hp[l],       h1 = hp[l + 64];
        const float2 h2 = hp[l + 128], h3 = hp[l + 192];
        const double2 x1 = make_double2((double)a0.x * (double)h0.x,
                                        (double)a0.y * (double)h0.y);
        const double2 x2 = make_double2((double)a1.x * (double)h1.x,
                                        (double)a1.y * (double)h1.y);
        const double2 y1 = make_double2((double)a2.x * (double)h2.x,
                                        (double)a2.y * (double)h2.y);
        const double2 y2 = make_double2((double)a3.x * (double)h3.x,
                                        (double)a3.y * (double)h3.y);
        bfly4d(0, l, make_double2(tq.x, tq.y), make_double2(tq.z, tq.w),
               x1, y1, x2, y2, W);
    }
    __builtin_amdgcn_wave_barrier();
    {   // stage 2 in place
        const double4 tq = twq[64 + l];
        const double2 x1 = W[IDX(l)],      y1 = W[IDX(l + 128)];
        const double2 x2 = W[IDX(l + 64)], y2 = W[IDX(l + 192)];
        bfly4d(2, l, make_double2(tq.x, tq.y), make_double2(tq.z, tq.w),
               x1, y1, x2, y2, W);
    }
    __builtin_amdgcn_wave_barrier();
    {   // stage 4 in place
        const double4 tq = twq[128 + l];
        const double2 x1 = W[IDX(l)],      y1 = W[IDX(l + 128)];
        const double2 x2 = W[IDX(l + 64)], y2 = W[IDX(l + 192)];
        bfly4d(4, l, make_double2(tq.x, tq.y), make_double2(tq.z, tq.w),
               x1, y1, x2, y2, W);
    }
    __builtin_amdgcn_wave_barrier();
    {   // stage 6: twiddles are (1,0) -> skip muls
        const double2 x1 = W[IDX(l)],      y1 = W[IDX(l + 128)];
        const double2 x2 = W[IDX(l + 64)], y2 = W[IDX(l + 192)];
        const double2 u1 = d2add(x1, y1);
        const double2 v1 = d2sub(x1, y1);
        const double2 u2 = d2add(x2, y2);
        const double2 m  = d2sub(x2, y2);
        const double2 v2 = make_double2(m.y, -m.x);   // -i*m
        W[IDX(l)]       = d2add(u1, u2);
        W[IDX(l + 64)]  = d2add(v1, v2);
        W[IDX(l + 128)] = d2sub(u1, u2);
        W[IDX(l + 192)] = d2sub(v1, v2);
    }
    __builtin_amdgcn_wave_barrier();
    {   // untangle -> pwr (reads hoisted above overlay writes)
        const double4 tq = twq[192 + l];
        const double2 zk0 = W[IDX(l)];
        const double2 zc0 = W[IDX((256 - l) & 255)];
        const double2 zk1 = W[IDX(l + 64)];
        const double2 zc1 = W[IDX(192 - l)];
        const double2 zm  = W[IDX(128)];
        __builtin_amdgcn_wave_barrier();   // reads done; now write
        {
            const double Sr = zk0.x + zc0.x, Si = zk0.y + zc0.y;
            const double Dr = zk0.x - zc0.x;
            const double E = 0.5 * Sr, T = 0.5 * (tq.x * Si - tq.y * Dr);
            const double a = (E + T) * (1.0 / 512.0);
            const double b = (E - T) * (1.0 / 512.0);
            pwr[l]       = a * a;
            pwr[256 - l] = b * b;          // l=0: Nyquist
        }
        {
            const double Sr = zk1.x + zc1.x, Si = zk1.y + zc1.y;
            const double Dr = zk1.x - zc1.x;
            const double E = 0.5 * Sr, T = 0.5 * (tq.z * Si - tq.w * Dr);
            const double a = (E + T) * (1.0 / 512.0);
            const double b = (E - T) * (1.0 / 512.0);
            pwr[l + 64]  = a * a;
            pwr[192 - l] = b * b;
        }
        if (l == 0) {   // k = 128: wk = (0,1) -> rex = zk.re exactly
            const double v = zm.x * (1.0 / 512.0);
            pwr[128] = v * v;
        }
        if (l < 3) pwr[257 + l] = 0.0;     // pad for last 4-bin group
    }
    __builtin_amdgcn_wave_barrier();

    // mel over compact support, f64
    double acc = 0.0;
    if (l < 60) {
        const int mel = l % 20;
        const int sub = l / 20;
        const int mw  = meta[mel];
        const int g0m = mw & 0xffff;
        const int ngm = mw >> 16;
        const float4* wrow = wc + mel * WCSTRIDE;
        const double2* pw2 = (const double2*)pwr + 2 * g0m;
        for (int j = sub; j < ngm; j += 3) {
            const float4 w4 = wrow[j];
            const double2 q0 = pw2[2 * j];
            const double2 q1 = pw2[2 * j + 1];
            acc = fma((double)w4.x, q0.x, acc);
            acc = fma((double)w4.y, q0.y, acc);
            acc = fma((double)w4.z, q1.x, acc);
            acc = fma((double)w4.w, q1.y, acc);
        }
    }
    const double p1 = __shfl(acc, l + 20);
    const double p2 = __shfl(acc, l + 40);
    if (l < 20) {
        double v = acc + p1 + p2;
        if (v == 0.0) v = 2.220446049250313e-16;
        out[(size_t)f * 20 + l] = (float)floor(log2(v));
    }
    __builtin_amdgcn_wave_barrier();   // W reuse by next repair
}

// ---------------------------------------------------------------- prep ----
__global__ void prep_full(const float* __restrict__ fb,
                          float4* __restrict__ twp,    // (256,) f32 per-lane
                          double4* __restrict__ twq,   // (256,) f64 per-lane
                          float4* __restrict__ wc,     // (20, WCSTRIDE)
                          int*    __restrict__ meta) { // (20,) g0 | ng<<16
    __shared__ float2 s_tw[256];
    __shared__ double sc[256], ss[256];
    __shared__ int slo[20], shi[20], sg0[20], sng[20];
    const int t = threadIdx.x;  // 256
    double s, c;
    sincospi((double)t * (1.0 / 256.0), &s, &c);
    sc[t] = c; ss[t] = s;
    s_tw[t] = make_float2((float)c, (float)s);
    if (t < 20) { slo[t] = 257; shi[t] = 0; }
    __syncthreads();

    // Parallel nonzero-support scan: 12 threads per mel row, 22 bins each.
    if (t < 240) {
        const int m = t / 12, part = t % 12;
        const int k0 = part * 22;
        int k1 = k0 + 22; if (k1 > 257) k1 = 257;
        int lo = 257, hi = 0;
        for (int k = k0; k < k1; k++)
            if (fb[m * 257 + k] > 0.0f) { if (k < lo) lo = k; hi = k + 1; }
        if (hi > lo) { atomicMin(&slo[m], lo); atomicMax(&shi[m], hi); }
    }
    __syncthreads();

    if (t < 20) {
        int lo = slo[t], hi = shi[t];
        if (hi <= lo) { lo = 0; hi = 1; }         // degenerate guard
        int g0 = lo >> 2;
        int ng = ((hi + 3) >> 2) - g0;
        if (ng > WCSTRIDE) ng = WCSTRIDE;         // never binds for this bank
        sg0[t] = g0; sng[t] = ng;
        meta[t] = g0 | (ng << 16);
    }
    if (t < 64) {
        // stage 0: w1 = tw[2l], w2 = tw[4l]   (4*63 = 252 < 256)
        const float2 a0 = s_tw[2 * t],        b0 = s_tw[4 * t];
        twp[t]        = make_float4(a0.x, a0.y, b0.x, b0.y);
        const float2 a2 = s_tw[8 * (t >> 2)], b2 = s_tw[16 * (t >> 2)];
        twp[64 + t]   = make_float4(a2.x, a2.y, b2.x, b2.y);
        const float2 a4 = s_tw[32 * (t >> 4)], b4 = s_tw[64 * (t >> 4)];
        twp[128 + t]  = make_float4(a4.x, a4.y, b4.x, b4.y);
        const float2 u0 = s_tw[t],            u1 = s_tw[t + 64];
        twp[192 + t]  = make_float4(u0.x, u0.y, u1.x, u1.y);
        // f64 versions (inline repair)
        twq[t]       = make_double4(sc[2*t], ss[2*t], sc[4*t], ss[4*t]);
        twq[64 + t]  = make_double4(sc[8*(t>>2)],  ss[8*(t>>2)],
                                    sc[16*(t>>2)], ss[16*(t>>2)]);
        twq[128 + t] = make_double4(sc[32*(t>>4)], ss[32*(t>>4)],
                                    sc[64*(t>>4)], ss[64*(t>>4)]);
        twq[192 + t] = make_double4(sc[t], ss[t], sc[t+64], ss[t+64]);
    }
    __syncthreads();

    for (int i = t; i < 20 * WCSTRIDE; i += 256) {
        const int m = i / WCSTRIDE, j = i % WCSTRIDE;
        float4 v = make_float4(0.0f, 0.0f, 0.0f, 0.0f);
        if (j < sng[m]) {
            const int b = (sg0[m] + j) * 4;
            const float* row = fb + m * 257;
            v.x = (b + 0 < 257) ? row[b + 0] : 0.0f;
            v.y = (b + 1 < 257) ? row[b + 1] : 0.0f;
            v.z = (b + 2 < 257) ? row[b + 2] : 0.0f;
            v.w = (b + 3 < 257) ? row[b + 3] : 0.0f;
        }
        wc[i] = v;
    }
}

__global__ void prep_tw64(double* __restrict__ tw64) {
    const int t = threadIdx.x;
    double s, c;
    sincospi((double)t * (1.0 / 256.0), &s, &c);
    tw64[t]       = c;
    tw64[256 + t] = s;
}

// -------------------------------------------------------------- phase 1 ----
// fp32: 4 frames per wave (2 chains x 2 packed), 4 waves per 256-thread
// block (16 frames/block). LDS = 8*288*16 = 36864 B -> 4 blocks/CU.
// Flagged frames repaired inline in f64 by the owning wave (no phase2).
__global__ __launch_bounds__(256, 4) void phase1(
    const float* __restrict__ x,      // (frames, 512)
    const float* __restrict__ hw,     // (512,)
    const float4* __restrict__ twp,   // (256,) f32 per-lane twiddles (ws)
    const double4* __restrict__ twq,  // (256,) f64 per-lane twiddles (ws)
    const float4* __restrict__ wc,    // (20, WCSTRIDE) compact filter bank
    const int*    __restrict__ meta,  // (20,) g0 | ng<<16
    float* __restrict__ out)          // (frames, 20)
{
    __shared__ __align__(16) float4 buf[8][288];   // 288 = IDX(255)+2 pad

    const int t = threadIdx.x;
    const int w = t >> 6;     // wave id
    const int l = t & 63;     // lane
    const int base = (blockIdx.x * 4 + w) * 4;
    const int fg0 = base, fg1 = base + 1, fg2 = base + 2, fg3 = base + 3;

    const float4 tp0 = twp[l];
    const float4 tp2 = twp[64 + l];
    const float4 tp4 = twp[128 + l];
    const float4 tpU = twp[192 + l];
    const float2 w0s = make_float2(tp0.x, tp0.y), w0d = make_float2(tp0.z, tp0.w);
    const float2 w2s = make_float2(tp2.x, tp2.y), w2d = make_float2(tp2.z, tp2.w);
    const float2 w4s = make_float2(tp4.x, tp4.y), w4d = make_float2(tp4.z, tp4.w);

    float4* const WA = &buf[2 * w][0];
    float4* const WB = &buf[2 * w + 1][0];

    const float2* hp = (const float2*)hw;
    const float2 h0 = hp[l],       h1 = hp[l + 64];
    const float2 h2 = hp[l + 128], h3 = hp[l + 192];

    load_stage0(x, fg0, fg1, l, h0, h1, h2, h3, w0s, w0d, WA);
    load_stage0(x, fg2, fg3, l, h0, h1, h2, h3, w0s, w0d, WB);
    __builtin_amdgcn_wave_barrier();   // in-wave DS order; pin compiler

    {
        const float4 ax1 = WA[IDX(l)],      ay1 = WA[IDX(l + 128)];
        const float4 ax2 = WA[IDX(l + 64)], ay2 = WA[IDX(l + 192)];
        const float4 bx1 = WB[IDX(l)],      by1 = WB[IDX(l + 128)];
        const float4 bx2 = WB[IDX(l + 64)], by2 = WB[IDX(l + 192)];
        bfly4(2, l, w2s, w2d, ax1, ay1, ax2, ay2, WA);
        bfly4(2, l, w2s, w2d, bx1, by1, bx2, by2, WB);
        __builtin_amdgcn_wave_barrier();
    }
    {
        const float4 ax1 = WA[IDX(l)],      ay1 = WA[IDX(l + 128)];
        const float4 ax2 = WA[IDX(l + 64)], ay2 = WA[IDX(l + 192)];
        const float4 bx1 = WB[IDX(l)],      by1 = WB[IDX(l + 128)];
        const float4 bx2 = WB[IDX(l + 64)], by2 = WB[IDX(l + 192)];
        bfly4(4, l, w4s, w4d, ax1, ay1, ax2, ay2, WA);
        bfly4(4, l, w4s, w4d, bx1, by1, bx2, by2, WB);
        __builtin_amdgcn_wave_barrier();
    }
    // Stage s = 6: j = 0 for every lane -> twiddles are (1,0): skip muls.
    {
        const float4 ax1 = WA[IDX(l)],      ay1 = WA[IDX(l + 128)];
        const float4 ax2 = WA[IDX(l + 64)], ay2 = WA[IDX(l + 192)];
        const float4 bx1 = WB[IDX(l)],      by1 = WB[IDX(l + 128)];
        const float4 bx2 = WB[IDX(l + 64)], by2 = WB[IDX(l + 192)];
        {
            const float4 u1 = f4add(ax1, ay1);
            const float4 v1 = f4sub(ax1, ay1);
            const float4 u2 = f4add(ax2, ay2);
            const float4 m  = f4sub(ax2, ay2);
            const float4 v2 = make_float4(m.y, -m.x, m.w, -m.z);   // -i*m
            WA[IDX(l)]       = f4add(u1, u2);
            WA[IDX(l + 64)]  = f4add(v1, v2);
            WA[IDX(l + 128)] = f4sub(u1, u2);
            WA[IDX(l + 192)] = f4sub(v1, v2);
        }
        {
            const float4 u1 = f4add(bx1, by1);
            const float4 v1 = f4sub(bx1, by1);
            const float4 u2 = f4add(bx2, by2);
            const float4 m  = f4sub(bx2, by2);
            const float4 v2 = make_float4(m.y, -m.x, m.w, -m.z);
            WB[IDX(l)]       = f4add(u1, u2);
            WB[IDX(l + 64)]  = f4add(v1, v2);
            WB[IDX(l + 128)] = f4sub(u1, u2);
            WB[IDX(l + 192)] = f4sub(v1, v2);
        }
    }
    __builtin_amdgcn_wave_barrier();

    // Untangle -> Re(rfft)_k, /512, square; symmetric-pair trick.
    float2* const pwrA = (float2*)WA;       // 264 float2, unpadded
    float2* const pwrB = (float2*)WB;
    {
        const float4 zk0A = WA[IDX(l)];
        const float4 zc0A = WA[IDX((256 - l) & 255)];
        const float4 zk1A = WA[IDX(l + 64)];
        const float4 zc1A = WA[IDX(192 - l)];
        const float4 zmA  = WA[IDX(128)];
        const float4 zk0B = WB[IDX(l)];
        const float4 zc0B = WB[IDX((256 - l) & 255)];
        const float4 zk1B = WB[IDX(l + 64)];
        const float4 zc1B = WB[IDX(192 - l)];
        const float4 zmB  = WB[IDX(128)];
        const float2 u0 = make_float2(tpU.x, tpU.y);
        const float2 u1 = make_float2(tpU.z, tpU.w);
        __builtin_amdgcn_wave_barrier();         // reads done; now write

#define UNTANGLE_PAIR(zk, zc, wk, p, kk, kc)                                 \
        {                                                                    \
            const float Sr0 = zk.x + zc.x, Si0 = zk.y + zc.y;                \
            const float Dr0 = zk.x - zc.x;                                   \
            const float Sr1 = zk.z + zc.z, Si1 = zk.w + zc.w;                \
            const float Dr1 = zk.z - zc.z;                                   \
            const float E0 = 0.5f * Sr0;                                     \
            const float T0 = 0.5f * (wk.x * Si0 - wk.y * Dr0);               \
            const float E1 = 0.5f * Sr1;                                     \
            const float T1 = 0.5f * (wk.x * Si1 - wk.y * Dr1);               \
            const float a0 = (E0 + T0) * (1.0f / 512.0f);                    \
            const float a1 = (E1 + T1) * (1.0f / 512.0f);                    \
            const float b0 = (E0 - T0) * (1.0f / 512.0f);                    \
            const float b1 = (E1 - T1) * (1.0f / 512.0f);                    \
            p[kk] = make_float2(a0 * a0, a1 * a1);                           \
            p[kc] = make_float2(b0 * b0, b1 * b1);                           \
        }
        UNTANGLE_PAIR(zk0A, zc0A, u0, pwrA, l, 256 - l)        // l=0: Nyquist
        UNTANGLE_PAIR(zk1A, zc1A, u1, pwrA, l + 64, 192 - l)
        UNTANGLE_PAIR(zk0B, zc0B, u0, pwrB, l, 256 - l)
        UNTANGLE_PAIR(zk1B, zc1B, u1, pwrB, l + 64, 192 - l)
#undef UNTANGLE_PAIR
        if (l == 0) {   // k = 128: wk = (0,1) -> rex = zk.re exactly
            const float vA0 = zmA.x * (1.0f / 512.0f);
            const float vA1 = zmA.z * (1.0f / 512.0f);
            pwrA[128] = make_float2(vA0 * vA0, vA1 * vA1);
            const float vB0 = zmB.x * (1.0f / 512.0f);
            const float vB1 = zmB.z * (1.0f / 512.0f);
            pwrB[128] = make_float2(vB0 * vB0, vB1 * vB1);
        }
        if (l >= 57) {
            pwrA[257 + (l - 57)] = make_float2(0.0f, 0.0f);
            pwrB[257 + (l - 57)] = make_float2(0.0f, 0.0f);
        }
    }
    __builtin_amdgcn_wave_barrier();

    // Mel over COMPACT support, both chains.
    float aA = 0.0f, aB = 0.0f, aC = 0.0f, aD = 0.0f;
    if (l < 60) {
        const int mel = l % 20;
        const int sub = l / 20;
        const int mw  = meta[mel];
        const int g0m = mw & 0xffff;
        const int ngm = mw >> 16;
        const float4* wrow = wc + mel * WCSTRIDE;
        const float4* pwA4 = (const float4*)pwrA + 2 * g0m;
        const float4* pwB4 = (const float4*)pwrB + 2 * g0m;
        for (int j = sub; j < ngm; j += 3) {
            const float4 w4  = wrow[j];
            const float4 qa0 = pwA4[2 * j];
            const float4 qa1 = pwA4[2 * j + 1];
            const float4 qb0 = pwB4[2 * j];
            const float4 qb1 = pwB4[2 * j + 1];
            aA = fmaf(w4.w, qa1.z, fmaf(w4.z, qa1.x,
                 fmaf(w4.y, qa0.z, fmaf(w4.x, qa0.x, aA))));
            aB = fmaf(w4.w, qa1.w, fmaf(w4.z, qa1.y,
                 fmaf(w4.y, qa0.w, fmaf(w4.x, qa0.y, aB))));
            aC = fmaf(w4.w, qb1.z, fmaf(w4.z, qb1.x,
                 fmaf(w4.y, qb0.z, fmaf(w4.x, qb0.x, aC))));
            aD = fmaf(w4.w, qb1.w, fmaf(w4.z, qb1.y,
                 fmaf(w4.y, qb0.w, fmaf(w4.x, qb0.y, aD))));
        }
    }
    const float pA1 = __shfl(aA, l + 20), pA2 = __shfl(aA, l + 40);
    const float pB1 = __shfl(aB, l + 20), pB2 = __shfl(aB, l + 40);
    const float pC1 = __shfl(aC, l + 20), pC2 = __shfl(aC, l + 40);
    const float pD1 = __shfl(aD, l + 20), pD2 = __shfl(aD, l + 40);

    int fl0 = 0, fl1 = 0, fl2 = 0, fl3 = 0;
    if (l < 20) {
#define FINISH(acc, p1, p2, fg, flag)                                        \
        {                                                                    \
            const float v = acc + p1 + p2;                                   \
            float fl;                                                        \
            if (v < 1e-30f) { fl = -52.0f; flag = 1; }                       \
            else {                                                           \
                const float l2 = log2f(v);                                   \
                fl = floorf(l2);                                             \
                flag = (l2 - fl < MARGIN_L2) | ((fl + 1.0f - l2) < MARGIN_L2);\
            }                                                                \
            out[(size_t)fg * 20 + l] = fl;                                   \
        }
        FINISH(aA, pA1, pA2, fg0, fl0)
        FINISH(aB, pB1, pB2, fg1, fl1)
        FINISH(aC, pC1, pC2, fg2, fl2)
        FINISH(aD, pD1, pD2, fg3, fl3)
#undef FINISH
    }
    const unsigned long long b0 = __ballot(fl0);
    const unsigned long long b1 = __ballot(fl1);
    const unsigned long long b2 = __ballot(fl2);
    const unsigned long long b3 = __ballot(fl3);

    // Inline f64 repair of flagged frames (wave-uniform branches; reuses
    // WA's 4608 B as double2[288]; all pwrA/pwrB LDS reads completed above).
    if ((b0 | b1 | b2 | b3) != 0ULL) {
        __builtin_amdgcn_wave_barrier();
        double2* const DW = (double2*)WA;
        if (b0 != 0ULL) repair_f64(x, hw, twq, wc, meta, out, fg0, l, DW);
        if (b1 != 0ULL) repair_f64(x, hw, twq, wc, meta, out, fg1, l, DW);
        if (b2 != 0ULL) repair_f64(x, hw, twq, wc, meta, out, fg2, l, DW);
        if (b3 != 0ULL) repair_f64(x, hw, twq, wc, meta, out, fg3, l, DW);
    }
}

// ------------------------------------------------- fallback: all-f64 (R2) ----
__global__ __launch_bounds__(256) void f64_all(
    const float*  __restrict__ x,
    const float*  __restrict__ fb,
    const float*  __restrict__ hw,
    const double* __restrict__ tw,
    float* __restrict__ out)
{
    __shared__ double Are[256], Aim[256], Bre[256], Bim[256];
    __shared__ double ltc[256], lts[256];
    __shared__ double pwr[257];

    const int t = threadIdx.x;
    const int f = blockIdx.x;

    ltc[t] = tw[t];
    lts[t] = tw[256 + t];
    {
        const float2 xv = ((const float2*)x)[(size_t)f * 256 + t];
        const float2 hv = ((const float2*)hw)[t];
        Are[t] = (double)xv.x * (double)hv.x;
        Aim[t] = (double)xv.y * (double)hv.y;
    }
    __syncthreads();

    double* sre = Are; double* sim = Aim;
    double* dre = Bre; double* dim = Bim;
    const int p = t & 127;
    const int which = t >> 7;
#pragma unroll
    for (int s = 0; s < 8; s++) {
        const int j = p >> s;
        const double ar = sre[p],       ai = sim[p];
        const double br = sre[p + 128], bi = sim[p + 128];
        double orr, oi;
        int dpos;
        if (which) {
            const int idx = j << (s + 1);
            const double wr = ltc[idx];
            const double wi = -lts[idx];
            const double ur = ar - br, ui = ai - bi;
            orr = wr * ur - wi * ui;
            oi  = wr * ui + wi * ur;
            dpos = p + ((j + 1) << s);
        } else {
            orr = ar + br;
            oi  = ai + bi;
            dpos = p + (j << s);
        }
        dre[dpos] = orr;
        dim[dpos] = oi;
        __syncthreads();
        double* tmp;
        tmp = sre; sre = dre; dre = tmp;
        tmp = sim; sim = dim; dim = tmp;
    }

    {
        const double a = sre[t], b = sim[t];
        const int t2 = (256 - t) & 255;
        const double c = sre[t2], d = sim[t2];
        const double rex = 0.5 * (a + c)
                         + 0.5 * (ltc[t] * (b + d) - lts[t] * (a - c));
        const double v = rex * (1.0 / 512.0);
        pwr[t] = v * v;
        if (t == 0) {
            const double vn = (a - b) * (1.0 / 512.0);
            pwr[256] = vn * vn;
        }
    }
    __syncthreads();

    if (t < 160) {
        const int mel = t >> 3;
        const int sub = t & 7;
        const float* wrow = fb + mel * 257;
        double acc = 0.0;
        for (int k = sub; k < 257; k += 8)
            acc = fma((double)wrow[k], pwr[k], acc);
        acc += __shfl_down(acc, 4, 8);
        acc += __shfl_down(acc, 2, 8);
        acc += __shfl_down(acc, 1, 8);
        if (sub == 0) {
            double v = acc;
            if (v == 0.0) v = 2.220446049250313e-16;
            out[(size_t)f * 20 + mel] = (float)floor(log2(v));
        }
    }
}

// ---------------------------------------------------------------- launch ----
extern "C" void kernel_launch(void* const* d_in, const int* in_sizes, int n_in,
                              void* d_out, int out_size, void* d_ws, size_t ws_size,
                              hipStream_t stream) {
    const float* x  = (const float*)d_in[0];   // (4096, 32, 512) f32
    const float* fb = (const float*)d_in[1];   // (20, 257) f32
    const float* hw = (const float*)d_in[2];   // (512,) f32
    float* out = (float*)d_out;

    const int frames = in_sizes[0] / 512;      // 131072

    char* ws = (char*)d_ws;
    // main path layout:
    float4*  twp  = (float4*)ws;                         // 4096 B
    double4* twq  = (double4*)(ws + 4096);               // 8192 B
    float4*  wc   = (float4*)(ws + 12288);               // 6400 B
    int*     meta = (int*)(ws + 18688);                  // 80 B
    // fallback layout:
    double*  tw64 = (double*)ws;                         // 4096 B

    if (ws_size >= 32768 && (frames % 16) == 0) {
        prep_full<<<1, 256, 0, stream>>>(fb, twp, twq, wc, meta);
        phase1<<<frames / 16, 256, 0, stream>>>(x, hw, twp, twq, wc, meta, out);
    } else {
        prep_tw64<<<1, 256, 0, stream>>>(tw64);
        f64_all<<<frames, 256, 0, stream>>>(x, fb, hw, tw64, out);
    }
}